// Round 1
// baseline (2452.085 us; speedup 1.0000x reference)
//
#include <hip/hip_runtime.h>
#include <cstdint>
#include <cstddef>

// ---------------- types & helpers ----------------
typedef __attribute__((ext_vector_type(4))) float floatx4;
typedef __attribute__((ext_vector_type(8))) short short8;

__device__ __forceinline__ short f2bf(float x) {
  union { float f; unsigned u; } c; c.f = x;
  unsigned r = (c.u + 0x7FFFu + ((c.u >> 16) & 1u)) >> 16;  // RNE
  return (short)r;
}

__device__ __forceinline__ floatx4 mfma16(short8 a, short8 b, floatx4 c) {
  return __builtin_amdgcn_mfma_f32_16x16x32_bf16(a, b, c, 0, 0, 0);
}

// async global->LDS, 16B per lane; LDS dest must be wave-uniform (lane*16 appended by HW)
template <typename T>
__device__ __forceinline__ void gl_lds16(const T* g, T* l) {
  __builtin_amdgcn_global_load_lds(
      (__attribute__((address_space(1))) void*)g,
      (__attribute__((address_space(3))) void*)l, 16, 0, 0);
}

// ---------------- rmsnorm (+silu) with optional replicate-pad ----------------
// PAD: writes [10][34][34][512] bf16 (time pad (2,0), spatial (1,1), edge mode)
// else: writes [8192][512] bf16.  One wave per output token.
template <bool PAD, bool SILU>
__global__ __launch_bounds__(256) void norm_kernel(const float* __restrict__ src,
                                                   const float* __restrict__ gamma,
                                                   short* __restrict__ dst) {
  const int tid = threadIdx.x;
  const int wv = tid >> 6, lane = tid & 63;
  const int id = blockIdx.x * 4 + wv;
  int srow;
  if (PAD) {
    int tp = id / 1156, rem = id - tp * 1156;
    int hp = rem / 34, wp = rem - hp * 34;
    int t = tp - 2; t = t < 0 ? 0 : t;
    int h = hp - 1; h = h < 0 ? 0 : (h > 31 ? 31 : h);
    int w = wp - 1; w = w < 0 ? 0 : (w > 31 ? 31 : w);
    srow = (t << 10) + (h << 5) + w;
  } else {
    srow = id;
  }
  const float* sp = src + (size_t)srow * 512 + lane * 8;
  float4 v0 = *(const float4*)sp;
  float4 v1 = *(const float4*)(sp + 4);
  float a[8] = {v0.x, v0.y, v0.z, v0.w, v1.x, v1.y, v1.z, v1.w};
  float ss = 0.f;
#pragma unroll
  for (int i = 0; i < 8; ++i) ss += a[i] * a[i];
#pragma unroll
  for (int off = 32; off > 0; off >>= 1) ss += __shfl_xor(ss, off);
  const float scale = 22.627416997969522f / (sqrtf(ss) + 1e-8f);  // sqrt(512)/(||x||+eps)
  const float* gp = gamma + lane * 8;
  float4 g0 = *(const float4*)gp;
  float4 g1 = *(const float4*)(gp + 4);
  float g[8] = {g0.x, g0.y, g0.z, g0.w, g1.x, g1.y, g1.z, g1.w};
  short8 ov;
#pragma unroll
  for (int i = 0; i < 8; ++i) {
    float y = a[i] * scale * g[i];
    if (SILU) y = y / (1.f + __expf(-y));
    ov[i] = f2bf(y);
  }
  *(short8*)(dst + (size_t)id * 512 + lane * 8) = ov;
}

// ---------------- weight transpose fp32 [R][C] -> bf16 [C][R] ----------------
__global__ __launch_bounds__(256) void transpose_w(const float* __restrict__ src,
                                                   short* __restrict__ dst, int R, int C) {
  __shared__ float t[32][33];
  const int tx = threadIdx.x & 31, ty = threadIdx.x >> 5;
  const int r0 = (int)blockIdx.x << 5, c0 = (int)blockIdx.y << 5;
#pragma unroll
  for (int i = 0; i < 4; ++i)
    t[ty + i * 8][tx] = src[(size_t)(r0 + ty + i * 8) * C + c0 + tx];
  __syncthreads();
#pragma unroll
  for (int i = 0; i < 4; ++i)
    dst[(size_t)(c0 + ty + i * 8) * R + r0 + tx] = f2bf(t[tx][ty + i * 8]);
}

// ---------------- bf16 transpose [R][C] -> [C][R] (for V -> V^T) ----------------
__global__ __launch_bounds__(256) void transpose_b16(const short* __restrict__ src,
                                                     short* __restrict__ dst, int R, int C) {
  __shared__ short t[32][33];
  const int tx = threadIdx.x & 31, ty = threadIdx.x >> 5;
  const int r0 = (int)blockIdx.x << 5, c0 = (int)blockIdx.y << 5;
#pragma unroll
  for (int i = 0; i < 4; ++i)
    t[ty + i * 8][tx] = src[(size_t)(r0 + ty + i * 8) * C + c0 + tx];
  __syncthreads();
#pragma unroll
  for (int i = 0; i < 4; ++i)
    dst[(size_t)(c0 + ty + i * 8) * R + r0 + tx] = t[tx][ty + i * 8];
}

// ---------------- implicit-GEMM causal conv3d ----------------
// out[m][co] = sum_{tap,cin} Xp[(t+dt)*1156+(h+dh)*34+(w+dw)][cin] * WT[co][tap*512+cin] + bias (+res)
// tile 128x128, BK=32, 432 K-iters, m97 2-barrier structure.
template <bool HAS_RES>
__global__ __launch_bounds__(256) void conv_gemm(const short* __restrict__ Xp,
                                                 const short* __restrict__ WT,
                                                 const float* __restrict__ bias,
                                                 const float* __restrict__ res,
                                                 float* __restrict__ out) {
  __shared__ __attribute__((aligned(16))) short Alds[4096];
  __shared__ __attribute__((aligned(16))) short Blds[4096];
  const int tid = threadIdx.x;
  const int wv = tid >> 6, lane = tid & 63;
  const int m0 = (int)blockIdx.x << 7, n0 = (int)blockIdx.y << 7;

  int aoff[2], boff[2];
#pragma unroll
  for (int j = 0; j < 2; ++j) {
    const int chunk = wv * 2 + j;
    const int m = m0 + chunk * 16 + (lane >> 2);
    const int t = m >> 10, h = (m >> 5) & 31, w = m & 31;
    aoff[j] = (t * 1156 + h * 34 + w) * 512 + (lane & 3) * 8;
    const int n = n0 + chunk * 16 + (lane >> 2);
    boff[j] = n * 13824 + (lane & 3) * 8;
  }
  const int wm = (wv & 1) << 6, wn = (wv >> 1) << 6;
  floatx4 acc[4][4];
#pragma unroll
  for (int i = 0; i < 4; ++i)
#pragma unroll
    for (int j = 0; j < 4; ++j) acc[i][j] = 0.f;

  const int la = (lane & 15) * 32 + (lane >> 4) * 8;

  for (int kk = 0; kk < 432; ++kk) {
    const int tap = kk >> 4;
    const int cin0 = (kk & 15) << 5;
    const int dt = tap / 9;
    const int r9 = tap - dt * 9;
    const int dh = r9 / 3;
    const int dw = r9 - dh * 3;
    const int tapoff = (dt * 1156 + dh * 34 + dw) * 512 + cin0;
#pragma unroll
    for (int j = 0; j < 2; ++j) {
      const int chunk = wv * 2 + j;
      gl_lds16(Xp + aoff[j] + tapoff, &Alds[chunk * 512]);
      gl_lds16(WT + boff[j] + (kk << 5), &Blds[chunk * 512]);
    }
    __syncthreads();
    short8 af[4], bf[4];
#pragma unroll
    for (int i = 0; i < 4; ++i) af[i] = *(const short8*)&Alds[(wm + i * 16) * 32 + la];
#pragma unroll
    for (int j = 0; j < 4; ++j) bf[j] = *(const short8*)&Blds[(wn + j * 16) * 32 + la];
#pragma unroll
    for (int i = 0; i < 4; ++i)
#pragma unroll
      for (int j = 0; j < 4; ++j) acc[i][j] = mfma16(af[i], bf[j], acc[i][j]);
    __syncthreads();
  }

  const int rbase = m0 + wm + (lane >> 4) * 4;
#pragma unroll
  for (int i = 0; i < 4; ++i) {
    const int row = rbase + i * 16;
#pragma unroll
    for (int j = 0; j < 4; ++j) {
      const int col = n0 + wn + j * 16 + (lane & 15);
      const float bz = bias[col];
#pragma unroll
      for (int r = 0; r < 4; ++r) {
        const size_t idx = (size_t)(row + r) * 512 + col;
        float v = acc[i][j][r] + bz;
        if (HAS_RES) v += res[idx];
        out[idx] = v;
      }
    }
  }
}

// ---------------- generic GEMM  C = A(MxK) * BT(NxK)^T ----------------
// EPI=0: bf16 out split across 3 buffers of 512 cols each (QKV), bias per range.
// EPI=1: fp32 out = acc + bias + res  (proj + identity; in-place-safe).
template <int EPI>
__global__ __launch_bounds__(256) void gemm_bt(const short* __restrict__ A,
                                               const short* __restrict__ BT, int kdim,
                                               const float* __restrict__ b0,
                                               const float* __restrict__ b1,
                                               const float* __restrict__ b2,
                                               short* __restrict__ o0,
                                               short* __restrict__ o1,
                                               short* __restrict__ o2,
                                               float* oF, const float* res) {
  __shared__ __attribute__((aligned(16))) short Alds[4096];
  __shared__ __attribute__((aligned(16))) short Blds[4096];
  const int tid = threadIdx.x;
  const int wv = tid >> 6, lane = tid & 63;
  const int m0 = (int)blockIdx.x << 7, n0 = (int)blockIdx.y << 7;
  int aoff[2], boff[2];
#pragma unroll
  for (int j = 0; j < 2; ++j) {
    const int chunk = wv * 2 + j;
    aoff[j] = (m0 + chunk * 16 + (lane >> 2)) * kdim + (lane & 3) * 8;
    boff[j] = (n0 + chunk * 16 + (lane >> 2)) * kdim + (lane & 3) * 8;
  }
  const int wm = (wv & 1) << 6, wn = (wv >> 1) << 6;
  floatx4 acc[4][4];
#pragma unroll
  for (int i = 0; i < 4; ++i)
#pragma unroll
    for (int j = 0; j < 4; ++j) acc[i][j] = 0.f;
  const int la = (lane & 15) * 32 + (lane >> 4) * 8;
  const int kiters = kdim >> 5;

  for (int kk = 0; kk < kiters; ++kk) {
#pragma unroll
    for (int j = 0; j < 2; ++j) {
      const int chunk = wv * 2 + j;
      gl_lds16(A + aoff[j] + (kk << 5), &Alds[chunk * 512]);
      gl_lds16(BT + boff[j] + (kk << 5), &Blds[chunk * 512]);
    }
    __syncthreads();
    short8 af[4], bf[4];
#pragma unroll
    for (int i = 0; i < 4; ++i) af[i] = *(const short8*)&Alds[(wm + i * 16) * 32 + la];
#pragma unroll
    for (int j = 0; j < 4; ++j) bf[j] = *(const short8*)&Blds[(wn + j * 16) * 32 + la];
#pragma unroll
    for (int i = 0; i < 4; ++i)
#pragma unroll
      for (int j = 0; j < 4; ++j) acc[i][j] = mfma16(af[i], bf[j], acc[i][j]);
    __syncthreads();
  }

  const int rbase = m0 + wm + (lane >> 4) * 4;
#pragma unroll
  for (int i = 0; i < 4; ++i) {
    const int row = rbase + i * 16;
#pragma unroll
    for (int j = 0; j < 4; ++j) {
      const int col = n0 + wn + j * 16 + (lane & 15);
      if (EPI == 0) {
        const int sel = col >> 9;
        const int c = col & 511;
        const float* bp = sel == 0 ? b0 : (sel == 1 ? b1 : b2);
        short* op = sel == 0 ? o0 : (sel == 1 ? o1 : o2);
        const float bz = bp[c];
#pragma unroll
        for (int r = 0; r < 4; ++r)
          op[(size_t)(row + r) * 512 + c] = f2bf(acc[i][j][r] + bz);
      } else {
        const float bz = b0[col];
#pragma unroll
        for (int r = 0; r < 4; ++r) {
          const size_t idx = (size_t)(row + r) * 512 + col;
          oF[idx] = acc[i][j][r] + bz + res[idx];
        }
      }
    }
  }
}

// ---------------- flash attention, block-causal by frame (1024 tok/frame) ----------------
// 32 q per block (2 waves x 16 rows), K staged in LDS (swizzled for frag reads),
// V^T streamed from global, P LDS round-trip (C-layout -> A-layout), online softmax (exp2).
__global__ __launch_bounds__(128) void attn_kernel(const short* __restrict__ Q,
                                                   const short* __restrict__ K,
                                                   const short* __restrict__ VT,
                                                   short* __restrict__ O) {
  __shared__ __attribute__((aligned(16))) short Klds[16384];  // 32 keys x 512 c, swizzled
  __shared__ __attribute__((aligned(16))) short Plds[2][512];
  const int tid = threadIdx.x;
  const int wv = tid >> 6, lane = tid & 63;
  const int q0 = (int)blockIdx.x << 5;
  const int f = q0 >> 10;
  const int nkt = (f + 1) << 5;  // (f+1)*1024/32 key-tiles

  short8 qf[16];
  {
    const short* qp = Q + (size_t)(q0 + wv * 16 + (lane & 15)) * 512 + (lane >> 4) * 8;
#pragma unroll
    for (int kc = 0; kc < 16; ++kc) qf[kc] = *(const short8*)(qp + kc * 32);
  }
  floatx4 o[32];
#pragma unroll
  for (int i = 0; i < 32; ++i) o[i] = 0.f;
  float mr[4] = {-1e30f, -1e30f, -1e30f, -1e30f};
  float lr[4] = {0.f, 0.f, 0.f, 0.f};
  const float c1 = 0.063758716f;  // log2(e)/sqrt(512)

  // staging: LDS linear in (wave,chunk,lane); global addr gives layout
  // elem(key,c)= (c/32)*1024 + ((c/8)%4)*256 + key*8 + c%8  -> frag reads 2-way-conflict free
  const int gbase = (lane & 31) * 512 + (wv << 8) + ((lane >> 5) << 3);
  const short* klbase = Klds + (lane >> 4) * 256 + (lane & 15) * 8;
  const short* vb = VT + (size_t)(lane & 15) * 8192 + (lane >> 4) * 8;

  for (int kt = 0; kt < nkt; ++kt) {
    const short* kbase = K + (size_t)kt * 16384 + gbase;
#pragma unroll
    for (int j = 0; j < 16; ++j)
      gl_lds16(kbase + (j >> 1) * 32 + (j & 1) * 16, &Klds[(wv * 16 + j) * 512]);
    __syncthreads();

    floatx4 s0 = 0.f, s1 = 0.f;
#pragma unroll
    for (int kc = 0; kc < 16; ++kc) {
      short8 k0 = *(const short8*)(klbase + kc * 1024);
      short8 k1 = *(const short8*)(klbase + kc * 1024 + 128);
      s0 = mfma16(qf[kc], k0, s0);
      s1 = mfma16(qf[kc], k1, s1);
    }

    float alpha[4];
    short pw0[4], pw1[4];
#pragma unroll
    for (int r = 0; r < 4; ++r) {
      float a0 = s0[r] * c1, a1 = s1[r] * c1;
      float mx = fmaxf(a0, a1);
      mx = fmaxf(mx, __shfl_xor(mx, 1));
      mx = fmaxf(mx, __shfl_xor(mx, 2));
      mx = fmaxf(mx, __shfl_xor(mx, 4));
      mx = fmaxf(mx, __shfl_xor(mx, 8));
      const float mn = fmaxf(mr[r], mx);
      const float al = exp2f(mr[r] - mn);
      const float p0 = exp2f(a0 - mn), p1 = exp2f(a1 - mn);
      float ps = p0 + p1;
      ps += __shfl_xor(ps, 1);
      ps += __shfl_xor(ps, 2);
      ps += __shfl_xor(ps, 4);
      ps += __shfl_xor(ps, 8);
      lr[r] = lr[r] * al + ps;
      mr[r] = mn;
      alpha[r] = al;
      pw0[r] = f2bf(p0);
      pw1[r] = f2bf(p1);
    }
    {
      short* pl = &Plds[wv][0] + ((lane >> 4) * 4) * 32 + (lane & 15);
#pragma unroll
      for (int r = 0; r < 4; ++r) {
        pl[r * 32] = pw0[r];
        pl[r * 32 + 16] = pw1[r];
      }
    }
    __syncthreads();
    const short8 pf = *(const short8*)&Plds[wv][(lane & 15) * 32 + (lane >> 4) * 8];
    const short* vbk = vb + kt * 32;
#pragma unroll
    for (int cn = 0; cn < 32; ++cn) {
      const short8 vf = *(const short8*)(vbk + (size_t)cn * 16 * 8192);
      floatx4 t = o[cn];
      t[0] *= alpha[0];
      t[1] *= alpha[1];
      t[2] *= alpha[2];
      t[3] *= alpha[3];
      o[cn] = mfma16(pf, vf, t);
    }
    __syncthreads();
  }

  float inv[4];
#pragma unroll
  for (int r = 0; r < 4; ++r) inv[r] = 1.f / lr[r];
  const int row = q0 + wv * 16 + (lane >> 4) * 4;
#pragma unroll
  for (int cn = 0; cn < 32; ++cn) {
    const int col = cn * 16 + (lane & 15);
#pragma unroll
    for (int r = 0; r < 4; ++r)
      O[(size_t)(row + r) * 512 + col] = f2bf(o[cn][r] * inv[r]);
  }
}

// ---------------- host ----------------
extern "C" void kernel_launch(void* const* d_in, const int* in_sizes, int n_in,
                              void* d_out, int out_size, void* d_ws, size_t ws_size,
                              hipStream_t stream) {
  const float* x     = (const float*)d_in[0];
  const float* r1_g1 = (const float*)d_in[1];
  const float* r1_w1 = (const float*)d_in[2];
  const float* r1_b1 = (const float*)d_in[3];
  const float* r1_g2 = (const float*)d_in[4];
  const float* r1_w2 = (const float*)d_in[5];
  const float* r1_b2 = (const float*)d_in[6];
  const float* at_g  = (const float*)d_in[7];
  const float* q_w   = (const float*)d_in[8];
  const float* q_b   = (const float*)d_in[9];
  const float* k_w   = (const float*)d_in[10];
  const float* k_b   = (const float*)d_in[11];
  const float* v_w   = (const float*)d_in[12];
  const float* v_b   = (const float*)d_in[13];
  const float* p_w   = (const float*)d_in[14];
  const float* p_b   = (const float*)d_in[15];
  const float* r2_g1 = (const float*)d_in[16];
  const float* r2_w1 = (const float*)d_in[17];
  const float* r2_b1 = (const float*)d_in[18];
  const float* r2_g2 = (const float*)d_in[19];
  const float* r2_w2 = (const float*)d_in[20];
  const float* r2_b2 = (const float*)d_in[21];
  float* out = (float*)d_out;

  char* ws = (char*)d_ws;
  size_t off = 0;
  auto alloc = [&](size_t bytes) -> void* {
    void* p = ws + off;
    off = (off + bytes + 255) & ~(size_t)255;
    return p;
  };
  short* wT    = (short*)alloc(27ull * 512 * 512 * 2);   // conv weight (reused x4)
  short* wqkvT = (short*)alloc(1536ull * 512 * 2);
  short* pwT   = (short*)alloc(512ull * 512 * 2);
  short* Xp    = (short*)alloc(10ull * 34 * 34 * 512 * 2);  // padded normed act
  float* Y     = (float*)alloc(8192ull * 512 * 4);          // conv1 out
  float* hA    = (float*)alloc(8192ull * 512 * 4);          // resnet1 out / final residual
  short* xn    = (short*)alloc(8192ull * 512 * 2);          // attn-norm out, reused as attn O
  short* Qb    = (short*)alloc(8192ull * 512 * 2);
  short* Kb    = (short*)alloc(8192ull * 512 * 2);
  short* Vb    = (short*)alloc(8192ull * 512 * 2);
  short* VTb   = (short*)alloc(8192ull * 512 * 2);
  (void)ws_size; (void)in_sizes; (void)n_in; (void)out_size;

  const dim3 b256(256), b128(128);

  // ----- resnet 1 -----
  transpose_w<<<dim3(432, 16), b256, 0, stream>>>(r1_w1, wT, 13824, 512);
  norm_kernel<true, true><<<2890, b256, 0, stream>>>(x, r1_g1, Xp);
  conv_gemm<false><<<dim3(64, 4), b256, 0, stream>>>(Xp, wT, r1_b1, nullptr, Y);
  transpose_w<<<dim3(432, 16), b256, 0, stream>>>(r1_w2, wT, 13824, 512);
  norm_kernel<true, true><<<2890, b256, 0, stream>>>(Y, r1_g2, Xp);
  conv_gemm<true><<<dim3(64, 4), b256, 0, stream>>>(Xp, wT, r1_b2, x, hA);

  // ----- attention -----
  norm_kernel<false, false><<<2048, b256, 0, stream>>>(hA, at_g, xn);
  transpose_w<<<dim3(16, 16), b256, 0, stream>>>(q_w, wqkvT, 512, 512);
  transpose_w<<<dim3(16, 16), b256, 0, stream>>>(k_w, wqkvT + 512 * 512, 512, 512);
  transpose_w<<<dim3(16, 16), b256, 0, stream>>>(v_w, wqkvT + 1024 * 512, 512, 512);
  transpose_w<<<dim3(16, 16), b256, 0, stream>>>(p_w, pwT, 512, 512);
  gemm_bt<0><<<dim3(64, 12), b256, 0, stream>>>(xn, wqkvT, 512, q_b, k_b, v_b,
                                                Qb, Kb, Vb, nullptr, nullptr);
  transpose_b16<<<dim3(256, 16), b256, 0, stream>>>(Vb, VTb, 8192, 512);
  attn_kernel<<<256, b128, 0, stream>>>(Qb, Kb, VTb, xn);
  gemm_bt<1><<<dim3(64, 4), b256, 0, stream>>>(xn, pwT, 512, p_b, nullptr, nullptr,
                                               nullptr, nullptr, nullptr, hA, hA);

  // ----- resnet 2 -----
  transpose_w<<<dim3(432, 16), b256, 0, stream>>>(r2_w1, wT, 13824, 512);
  norm_kernel<true, true><<<2890, b256, 0, stream>>>(hA, r2_g1, Xp);
  conv_gemm<false><<<dim3(64, 4), b256, 0, stream>>>(Xp, wT, r2_b1, nullptr, Y);
  transpose_w<<<dim3(432, 16), b256, 0, stream>>>(r2_w2, wT, 13824, 512);
  norm_kernel<true, true><<<2890, b256, 0, stream>>>(Y, r2_g2, Xp);
  conv_gemm<true><<<dim3(64, 4), b256, 0, stream>>>(Xp, wT, r2_b2, hA, out);
}

// Round 2
// 1794.521 us; speedup vs baseline: 1.3664x; 1.3664x over previous
//
#include <hip/hip_runtime.h>
#include <cstdint>
#include <cstddef>

// ---------------- types & helpers ----------------
typedef __attribute__((ext_vector_type(4))) float floatx4;
typedef __attribute__((ext_vector_type(8))) short short8;

__device__ __forceinline__ short f2bf(float x) {
  union { float f; unsigned u; } c; c.f = x;
  unsigned r = (c.u + 0x7FFFu + ((c.u >> 16) & 1u)) >> 16;  // RNE
  return (short)r;
}

__device__ __forceinline__ float bf2f(short x) {
  union { unsigned u; float f; } c; c.u = ((unsigned)(unsigned short)x) << 16;
  return c.f;
}

__device__ __forceinline__ floatx4 mfma16(short8 a, short8 b, floatx4 c) {
  return __builtin_amdgcn_mfma_f32_16x16x32_bf16(a, b, c, 0, 0, 0);
}

// async global->LDS, 16B per lane; LDS dest is wave-uniform base + lane*16
template <typename T>
__device__ __forceinline__ void gl_lds16(const T* g, T* l) {
  __builtin_amdgcn_global_load_lds(
      (__attribute__((address_space(1))) void*)g,
      (__attribute__((address_space(3))) void*)l, 16, 0, 0);
}

// ---------------- rmsnorm (+silu) with optional replicate-pad ----------------
template <bool PAD, bool SILU>
__global__ __launch_bounds__(256) void norm_kernel(const float* __restrict__ src,
                                                   const float* __restrict__ gamma,
                                                   short* __restrict__ dst) {
  const int tid = threadIdx.x;
  const int wv = tid >> 6, lane = tid & 63;
  const int id = blockIdx.x * 4 + wv;
  int srow;
  if (PAD) {
    int tp = id / 1156, rem = id - tp * 1156;
    int hp = rem / 34, wp = rem - hp * 34;
    int t = tp - 2; t = t < 0 ? 0 : t;
    int h = hp - 1; h = h < 0 ? 0 : (h > 31 ? 31 : h);
    int w = wp - 1; w = w < 0 ? 0 : (w > 31 ? 31 : w);
    srow = (t << 10) + (h << 5) + w;
  } else {
    srow = id;
  }
  const float* sp = src + (size_t)srow * 512 + lane * 8;
  float4 v0 = *(const float4*)sp;
  float4 v1 = *(const float4*)(sp + 4);
  float a[8] = {v0.x, v0.y, v0.z, v0.w, v1.x, v1.y, v1.z, v1.w};
  float ss = 0.f;
#pragma unroll
  for (int i = 0; i < 8; ++i) ss += a[i] * a[i];
#pragma unroll
  for (int off = 32; off > 0; off >>= 1) ss += __shfl_xor(ss, off);
  const float scale = 22.627416997969522f / (sqrtf(ss) + 1e-8f);  // sqrt(512)/(||x||+eps)
  const float* gp = gamma + lane * 8;
  float4 g0 = *(const float4*)gp;
  float4 g1 = *(const float4*)(gp + 4);
  float g[8] = {g0.x, g0.y, g0.z, g0.w, g1.x, g1.y, g1.z, g1.w};
  short8 ov;
#pragma unroll
  for (int i = 0; i < 8; ++i) {
    float y = a[i] * scale * g[i];
    if (SILU) y = y / (1.f + __expf(-y));
    ov[i] = f2bf(y);
  }
  *(short8*)(dst + (size_t)id * 512 + lane * 8) = ov;
}

// ---------------- weight transpose fp32 [R][C] -> bf16 [C][R] ----------------
__global__ __launch_bounds__(256) void transpose_w(const float* __restrict__ src,
                                                   short* __restrict__ dst, int R, int C) {
  __shared__ float t[32][33];
  const int tx = threadIdx.x & 31, ty = threadIdx.x >> 5;
  const int r0 = (int)blockIdx.x << 5, c0 = (int)blockIdx.y << 5;
#pragma unroll
  for (int i = 0; i < 4; ++i)
    t[ty + i * 8][tx] = src[(size_t)(r0 + ty + i * 8) * C + c0 + tx];
  __syncthreads();
#pragma unroll
  for (int i = 0; i < 4; ++i)
    dst[(size_t)(c0 + ty + i * 8) * R + r0 + tx] = f2bf(t[tx][ty + i * 8]);
}

// ---------------- implicit-GEMM causal conv3d, split-K 2-way ----------------
// partials only; bias/res folded into conv_combine.
__global__ __launch_bounds__(256) void conv_gemm_sp(const short* __restrict__ Xp,
                                                    const short* __restrict__ WT,
                                                    float* __restrict__ P0,
                                                    float* __restrict__ P1) {
  __shared__ __attribute__((aligned(16))) short Alds[4096];
  __shared__ __attribute__((aligned(16))) short Blds[4096];
  const int tid = threadIdx.x;
  const int wv = tid >> 6, lane = tid & 63;
  const int m0 = (int)blockIdx.x << 7, n0 = (int)blockIdx.y << 7;
  const int z = blockIdx.z;
  float* __restrict__ dst = z ? P1 : P0;

  int aoff[2], boff[2];
#pragma unroll
  for (int j = 0; j < 2; ++j) {
    const int chunk = wv * 2 + j;
    const int m = m0 + chunk * 16 + (lane >> 2);
    const int t = m >> 10, h = (m >> 5) & 31, w = m & 31;
    aoff[j] = (t * 1156 + h * 34 + w) * 512 + (lane & 3) * 8;
    const int n = n0 + chunk * 16 + (lane >> 2);
    boff[j] = n * 13824 + (lane & 3) * 8;
  }
  const int wm = (wv & 1) << 6, wn = (wv >> 1) << 6;
  floatx4 acc[4][4];
#pragma unroll
  for (int i = 0; i < 4; ++i)
#pragma unroll
    for (int j = 0; j < 4; ++j) acc[i][j] = 0.f;

  const int la = (lane & 15) * 32 + (lane >> 4) * 8;
  const int k0 = z * 216;

  for (int kk = k0; kk < k0 + 216; ++kk) {
    const int tap = kk >> 4;
    const int cin0 = (kk & 15) << 5;
    const int dt = tap / 9;
    const int r9 = tap - dt * 9;
    const int dh = r9 / 3;
    const int dw = r9 - dh * 3;
    const int tapoff = (dt * 1156 + dh * 34 + dw) * 512 + cin0;
#pragma unroll
    for (int j = 0; j < 2; ++j) {
      const int chunk = wv * 2 + j;
      gl_lds16(Xp + aoff[j] + tapoff, &Alds[chunk * 512]);
      gl_lds16(WT + boff[j] + (kk << 5), &Blds[chunk * 512]);
    }
    __syncthreads();
    short8 af[4], bf[4];
#pragma unroll
    for (int i = 0; i < 4; ++i) af[i] = *(const short8*)&Alds[(wm + i * 16) * 32 + la];
#pragma unroll
    for (int j = 0; j < 4; ++j) bf[j] = *(const short8*)&Blds[(wn + j * 16) * 32 + la];
#pragma unroll
    for (int i = 0; i < 4; ++i)
#pragma unroll
      for (int j = 0; j < 4; ++j) acc[i][j] = mfma16(af[i], bf[j], acc[i][j]);
    __syncthreads();
  }

  const int rbase = m0 + wm + (lane >> 4) * 4;
#pragma unroll
  for (int i = 0; i < 4; ++i) {
    const int row = rbase + i * 16;
#pragma unroll
    for (int j = 0; j < 4; ++j) {
      const int col = n0 + wn + j * 16 + (lane & 15);
#pragma unroll
      for (int r = 0; r < 4; ++r)
        dst[(size_t)(row + r) * 512 + col] = acc[i][j][r];
    }
  }
}

template <bool HAS_RES>
__global__ __launch_bounds__(256) void conv_combine(const float* __restrict__ P0,
                                                    const float* __restrict__ P1,
                                                    const float* __restrict__ bias,
                                                    const float* __restrict__ res,
                                                    float* __restrict__ out) {
  const size_t i = ((size_t)blockIdx.x * 256 + threadIdx.x) * 4;
  float4 a = *(const float4*)(P0 + i);
  float4 b = *(const float4*)(P1 + i);
  float4 bz = *(const float4*)(bias + (int)(i & 511));
  float4 r;
  r.x = a.x + b.x + bz.x;
  r.y = a.y + b.y + bz.y;
  r.z = a.z + b.z + bz.z;
  r.w = a.w + b.w + bz.w;
  if (HAS_RES) {
    float4 rs = *(const float4*)(res + i);
    r.x += rs.x; r.y += rs.y; r.z += rs.z; r.w += rs.w;
  }
  *(float4*)(out + i) = r;
}

// ---------------- generic GEMM  C = A(MxK) * BT(NxK)^T ----------------
// EPI=0: QKV — Q row-major bf16; K,V written pre-swizzled per 32-key tile:
//   K tile offset(key,c) = (c>>5)*1024 + ((c>>3)&3)*256 + key*8 + (c&7)
//   V tile offset(key,c) = ((key>>3)&3)*4096 + c*8 + (key&7)
// EPI=1: fp32 out = acc + bias + res (proj + identity; in-place-safe).
template <int EPI>
__global__ __launch_bounds__(256) void gemm_bt(const short* __restrict__ A,
                                               const short* __restrict__ BT, int kdim,
                                               const float* __restrict__ b0,
                                               const float* __restrict__ b1,
                                               const float* __restrict__ b2,
                                               short* __restrict__ o0,
                                               short* __restrict__ o1,
                                               short* __restrict__ o2,
                                               float* oF, const float* res) {
  __shared__ __attribute__((aligned(16))) short Alds[4096];
  __shared__ __attribute__((aligned(16))) short Blds[4096];
  const int tid = threadIdx.x;
  const int wv = tid >> 6, lane = tid & 63;
  const int m0 = (int)blockIdx.x << 7, n0 = (int)blockIdx.y << 7;
  int aoff[2], boff[2];
#pragma unroll
  for (int j = 0; j < 2; ++j) {
    const int chunk = wv * 2 + j;
    aoff[j] = (m0 + chunk * 16 + (lane >> 2)) * kdim + (lane & 3) * 8;
    boff[j] = (n0 + chunk * 16 + (lane >> 2)) * kdim + (lane & 3) * 8;
  }
  const int wm = (wv & 1) << 6, wn = (wv >> 1) << 6;
  floatx4 acc[4][4];
#pragma unroll
  for (int i = 0; i < 4; ++i)
#pragma unroll
    for (int j = 0; j < 4; ++j) acc[i][j] = 0.f;
  const int la = (lane & 15) * 32 + (lane >> 4) * 8;
  const int kiters = kdim >> 5;

  for (int kk = 0; kk < kiters; ++kk) {
#pragma unroll
    for (int j = 0; j < 2; ++j) {
      const int chunk = wv * 2 + j;
      gl_lds16(A + aoff[j] + (kk << 5), &Alds[chunk * 512]);
      gl_lds16(BT + boff[j] + (kk << 5), &Blds[chunk * 512]);
    }
    __syncthreads();
    short8 af[4], bf[4];
#pragma unroll
    for (int i = 0; i < 4; ++i) af[i] = *(const short8*)&Alds[(wm + i * 16) * 32 + la];
#pragma unroll
    for (int j = 0; j < 4; ++j) bf[j] = *(const short8*)&Blds[(wn + j * 16) * 32 + la];
#pragma unroll
    for (int i = 0; i < 4; ++i)
#pragma unroll
      for (int j = 0; j < 4; ++j) acc[i][j] = mfma16(af[i], bf[j], acc[i][j]);
    __syncthreads();
  }

  const int rbase = m0 + wm + (lane >> 4) * 4;
#pragma unroll
  for (int i = 0; i < 4; ++i) {
    const int row = rbase + i * 16;
#pragma unroll
    for (int j = 0; j < 4; ++j) {
      const int col = n0 + wn + j * 16 + (lane & 15);
      if (EPI == 0) {
        const int sel = col >> 9;
        const int c = col & 511;
        const float* bp = sel == 0 ? b0 : (sel == 1 ? b1 : b2);
        const float bz = bp[c];
#pragma unroll
        for (int r = 0; r < 4; ++r) {
          const int rr = row + r;
          const short v = f2bf(acc[i][j][r] + bz);
          if (sel == 0) {
            o0[(size_t)rr * 512 + c] = v;
          } else if (sel == 1) {
            o1[(size_t)(rr >> 5) * 16384 + ((c >> 5) << 10) + (((c >> 3) & 3) << 8) +
               ((rr & 31) << 3) + (c & 7)] = v;
          } else {
            o2[(size_t)(rr >> 5) * 16384 + (((rr >> 3) & 3) << 12) + (c << 3) + (rr & 7)] = v;
          }
        }
      } else {
        const float bz = b0[col];
#pragma unroll
        for (int r = 0; r < 4; ++r) {
          const size_t idx = (size_t)(row + r) * 512 + col;
          oF[idx] = acc[i][j][r] + bz + res[idx];
        }
      }
    }
  }
}

// ---------------- split-K flash attention partials ----------------
// block = (64 q, one 1024-key frame chunk). 4 waves, each owns 16 q rows.
// K staged to LDS (pre-swizzled global -> coalesced), V read direct from
// swizzled global (256B segments), P per-wave LDS round-trip (xor-swizzled).
__global__ __launch_bounds__(256, 2) void attn_partial(const short* __restrict__ Q,
                                                       const short* __restrict__ Ksw,
                                                       const short* __restrict__ Vsw,
                                                       short* __restrict__ OpA,
                                                       short* __restrict__ OpB,
                                                       float* __restrict__ Mp,
                                                       float* __restrict__ Lp) {
  __shared__ __attribute__((aligned(16))) short Klds[16384];
  __shared__ __attribute__((aligned(16))) short Plds[4][512];
  const int tid = threadIdx.x;
  const int wv = tid >> 6, lane = tid & 63;
  const int cl = lane & 15, quad = lane >> 4;
  const int qb = blockIdx.x;
  const int y = (int)blockIdx.y;
  int f = 0;
  while ((f + 1) * (f + 2) / 2 <= y) ++f;
  const int chunk = y - f * (f + 1) / 2;
  const int pidx = y * 16 + qb;
  const int q0 = (f << 10) + (qb << 6);

  short8 qf[16];
  {
    const short* qp = Q + (size_t)(q0 + wv * 16 + cl) * 512 + quad * 8;
#pragma unroll
    for (int kc = 0; kc < 16; ++kc) qf[kc] = *(const short8*)(qp + kc * 32);
  }
  floatx4 o[32];
#pragma unroll
  for (int i = 0; i < 32; ++i) o[i] = 0.f;
  float mr[4] = {-1e30f, -1e30f, -1e30f, -1e30f};
  float lr[4] = {0.f, 0.f, 0.f, 0.f};
  const float c1 = 0.063758716f;  // log2(e)/sqrt(512)
  const short* klb = Klds + quad * 256 + cl * 8;
  const int swr = ((cl >> 1) & 3) << 3;

  for (int kt = 0; kt < 32; ++kt) {
    const size_t tb = (size_t)((chunk << 5) + kt) * 16384;
    const short* kg = Ksw + tb;
#pragma unroll
    for (int j = 0; j < 8; ++j)
      gl_lds16(kg + ((j * 4 + wv) << 9) + lane * 8, &Klds[(j * 4 + wv) << 9]);
    __syncthreads();

    floatx4 s0 = 0.f, s1 = 0.f;
#pragma unroll
    for (int kc = 0; kc < 16; ++kc) {
      short8 k0 = *(const short8*)(klb + kc * 1024);
      short8 k1 = *(const short8*)(klb + kc * 1024 + 128);
      s0 = mfma16(qf[kc], k0, s0);
      s1 = mfma16(qf[kc], k1, s1);
    }

    float alpha[4];
#pragma unroll
    for (int r = 0; r < 4; ++r) {
      float a0 = s0[r] * c1, a1 = s1[r] * c1;
      float mx = fmaxf(a0, a1);
      mx = fmaxf(mx, __shfl_xor(mx, 1));
      mx = fmaxf(mx, __shfl_xor(mx, 2));
      mx = fmaxf(mx, __shfl_xor(mx, 4));
      mx = fmaxf(mx, __shfl_xor(mx, 8));
      const float mn = fmaxf(mr[r], mx);
      const float al = exp2f(mr[r] - mn);
      const float p0 = exp2f(a0 - mn), p1 = exp2f(a1 - mn);
      float ps = p0 + p1;
      ps += __shfl_xor(ps, 1);
      ps += __shfl_xor(ps, 2);
      ps += __shfl_xor(ps, 4);
      ps += __shfl_xor(ps, 8);
      lr[r] = lr[r] * al + ps;
      mr[r] = mn;
      alpha[r] = al;
      const int qlr = quad * 4 + r;
      const int sw = ((qlr >> 1) & 3) << 3;
      const int oi = qlr * 32 + (cl ^ sw);
      Plds[wv][oi] = f2bf(p0);
      Plds[wv][oi ^ 16] = f2bf(p1);
    }
    const short8 pf = *(const short8*)&Plds[wv][cl * 32 + ((quad << 3) ^ swr)];
    const short* vg = Vsw + tb + quad * 4096 + cl * 8;
#pragma unroll
    for (int cn = 0; cn < 32; ++cn) {
      const short8 vf = *(const short8*)(vg + cn * 128);
      floatx4 t = o[cn];
      t[0] *= alpha[0];
      t[1] *= alpha[1];
      t[2] *= alpha[2];
      t[3] *= alpha[3];
      o[cn] = mfma16(pf, vf, t);
    }
    __syncthreads();
  }

  short* base = pidx < 216 ? OpA + (size_t)pidx * 32768 : OpB + (size_t)(pidx - 216) * 32768;
  const int lrow0 = wv * 16 + quad * 4;
#pragma unroll
  for (int cn = 0; cn < 32; ++cn) {
    const int col = cn * 16 + cl;
#pragma unroll
    for (int r = 0; r < 4; ++r)
      base[(size_t)(lrow0 + r) * 512 + col] = f2bf(o[cn][r]);
  }
  if (cl == 0) {
#pragma unroll
    for (int r = 0; r < 4; ++r) {
      Mp[pidx * 64 + lrow0 + r] = mr[r];
      Lp[pidx * 64 + lrow0 + r] = lr[r];
    }
  }
}

// ---------------- attention combine: merge up to 8 chunk partials ----------------
__global__ __launch_bounds__(256) void attn_combine(const short* __restrict__ OpA,
                                                    const short* __restrict__ OpB,
                                                    const float* __restrict__ Mp,
                                                    const float* __restrict__ Lp,
                                                    short* __restrict__ O) {
  const int tid = threadIdx.x;
  const int wv = tid >> 6, lane = tid & 63;
  const int row = (int)blockIdx.x * 4 + wv;
  const int f = row >> 10, n = f + 1;
  const int qb = (row >> 6) & 15, lrow = row & 63;
  const int tri = f * (f + 1) / 2;
  float mv[8], lv[8];
#pragma unroll
  for (int ch = 0; ch < 8; ++ch) {
    if (ch < n) {
      const int pidx = (tri + ch) * 16 + qb;
      mv[ch] = Mp[pidx * 64 + lrow];
      lv[ch] = Lp[pidx * 64 + lrow];
    } else {
      mv[ch] = -1e30f;
      lv[ch] = 0.f;
    }
  }
  float M = mv[0];
#pragma unroll
  for (int ch = 1; ch < 8; ++ch) M = fmaxf(M, mv[ch]);
  float den = 0.f, acc[8];
#pragma unroll
  for (int i = 0; i < 8; ++i) acc[i] = 0.f;
#pragma unroll
  for (int ch = 0; ch < 8; ++ch) {
    if (ch < n) {
      const float w = exp2f(mv[ch] - M);
      den += w * lv[ch];
      const int pidx = (tri + ch) * 16 + qb;
      const short* b = pidx < 216 ? OpA + (size_t)pidx * 32768 : OpB + (size_t)(pidx - 216) * 32768;
      const short8 v = *(const short8*)(b + (size_t)lrow * 512 + lane * 8);
#pragma unroll
      for (int i = 0; i < 8; ++i) acc[i] += w * bf2f(v[i]);
    }
  }
  const float inv = 1.f / den;
  short8 ov;
#pragma unroll
  for (int i = 0; i < 8; ++i) ov[i] = f2bf(acc[i] * inv);
  *(short8*)(O + (size_t)row * 512 + lane * 8) = ov;
}

// ---------------- host ----------------
extern "C" void kernel_launch(void* const* d_in, const int* in_sizes, int n_in,
                              void* d_out, int out_size, void* d_ws, size_t ws_size,
                              hipStream_t stream) {
  const float* x     = (const float*)d_in[0];
  const float* r1_g1 = (const float*)d_in[1];
  const float* r1_w1 = (const float*)d_in[2];
  const float* r1_b1 = (const float*)d_in[3];
  const float* r1_g2 = (const float*)d_in[4];
  const float* r1_w2 = (const float*)d_in[5];
  const float* r1_b2 = (const float*)d_in[6];
  const float* at_g  = (const float*)d_in[7];
  const float* q_w   = (const float*)d_in[8];
  const float* q_b   = (const float*)d_in[9];
  const float* k_w   = (const float*)d_in[10];
  const float* k_b   = (const float*)d_in[11];
  const float* v_w   = (const float*)d_in[12];
  const float* v_b   = (const float*)d_in[13];
  const float* p_w   = (const float*)d_in[14];
  const float* p_b   = (const float*)d_in[15];
  const float* r2_g1 = (const float*)d_in[16];
  const float* r2_w1 = (const float*)d_in[17];
  const float* r2_b1 = (const float*)d_in[18];
  const float* r2_g2 = (const float*)d_in[19];
  const float* r2_w2 = (const float*)d_in[20];
  const float* r2_b2 = (const float*)d_in[21];
  float* out = (float*)d_out;

  char* ws = (char*)d_ws;
  size_t off = 0;
  auto alloc = [&](size_t bytes) -> void* {
    void* p = ws + off;
    off = (off + bytes + 255) & ~(size_t)255;
    return p;
  };
  short* wT    = (short*)alloc(27ull * 512 * 512 * 2);      // 14,155,776 B = 216 x 64KB partials
  short* wqkvT = (short*)alloc(1536ull * 512 * 2);
  short* pwT   = (short*)alloc(512ull * 512 * 2);
  short* Xp    = (short*)alloc(10ull * 34 * 34 * 512 * 2);  // padded act; +Y = partial region B
  float* Y     = (float*)alloc(8192ull * 512 * 4);
  float* hA    = (float*)alloc(8192ull * 512 * 4);
  short* xn    = (short*)alloc(8192ull * 512 * 2);          // + Qb = conv partial P0 (fp32)
  short* Qb    = (short*)alloc(8192ull * 512 * 2);
  short* Ksw   = (short*)alloc(8192ull * 512 * 2);          // + Vsw = conv partial P1 (fp32)
  short* Vsw   = (short*)alloc(8192ull * 512 * 2);
  float* Mp    = (float*)alloc(576ull * 64 * 4);
  float* Lp    = (float*)alloc(576ull * 64 * 4);
  (void)ws_size; (void)in_sizes; (void)n_in; (void)out_size;

  short* OpA = wT;          // 216 partials
  short* OpB = Xp;          // 360 partials (Xp+Y contiguous = 436 capacity)
  float* P0  = (float*)xn;  // xn+Qb contiguous = 16.78 MB fp32
  float* P1  = (float*)Ksw; // Ksw+Vsw contiguous

  const dim3 b256(256);
  const dim3 convg(64, 4, 2);

  // ----- resnet 1 -----
  transpose_w<<<dim3(432, 16), b256, 0, stream>>>(r1_w1, wT, 13824, 512);
  norm_kernel<true, true><<<2890, b256, 0, stream>>>(x, r1_g1, Xp);
  conv_gemm_sp<<<convg, b256, 0, stream>>>(Xp, wT, P0, P1);
  conv_combine<false><<<4096, b256, 0, stream>>>(P0, P1, r1_b1, nullptr, Y);
  transpose_w<<<dim3(432, 16), b256, 0, stream>>>(r1_w2, wT, 13824, 512);
  norm_kernel<true, true><<<2890, b256, 0, stream>>>(Y, r1_g2, Xp);
  conv_gemm_sp<<<convg, b256, 0, stream>>>(Xp, wT, P0, P1);
  conv_combine<true><<<4096, b256, 0, stream>>>(P0, P1, r1_b2, x, hA);

  // ----- attention -----
  norm_kernel<false, false><<<2048, b256, 0, stream>>>(hA, at_g, xn);
  transpose_w<<<dim3(16, 16), b256, 0, stream>>>(q_w, wqkvT, 512, 512);
  transpose_w<<<dim3(16, 16), b256, 0, stream>>>(k_w, wqkvT + 512 * 512, 512, 512);
  transpose_w<<<dim3(16, 16), b256, 0, stream>>>(v_w, wqkvT + 1024 * 512, 512, 512);
  transpose_w<<<dim3(16, 16), b256, 0, stream>>>(p_w, pwT, 512, 512);
  gemm_bt<0><<<dim3(64, 12), b256, 0, stream>>>(xn, wqkvT, 512, q_b, k_b, v_b,
                                                Qb, Ksw, Vsw, nullptr, nullptr);
  attn_partial<<<dim3(16, 36), b256, 0, stream>>>(Qb, Ksw, Vsw, OpA, OpB, Mp, Lp);
  attn_combine<<<2048, b256, 0, stream>>>(OpA, OpB, Mp, Lp, xn);
  gemm_bt<1><<<dim3(64, 4), b256, 0, stream>>>(xn, pwT, 512, p_b, nullptr, nullptr,
                                               nullptr, nullptr, nullptr, hA, hA);

  // ----- resnet 2 -----
  transpose_w<<<dim3(432, 16), b256, 0, stream>>>(r2_w1, wT, 13824, 512);
  norm_kernel<true, true><<<2890, b256, 0, stream>>>(hA, r2_g1, Xp);
  conv_gemm_sp<<<convg, b256, 0, stream>>>(Xp, wT, P0, P1);
  conv_combine<false><<<4096, b256, 0, stream>>>(P0, P1, r2_b1, nullptr, Y);
  transpose_w<<<dim3(432, 16), b256, 0, stream>>>(r2_w2, wT, 13824, 512);
  norm_kernel<true, true><<<2890, b256, 0, stream>>>(Y, r2_g2, Xp);
  conv_gemm_sp<<<convg, b256, 0, stream>>>(Xp, wT, P0, P1);
  conv_combine<true><<<4096, b256, 0, stream>>>(P0, P1, r2_b2, hA, out);
}

// Round 3
// 1308.645 us; speedup vs baseline: 1.8738x; 1.3713x over previous
//
#include <hip/hip_runtime.h>
#include <cstdint>
#include <cstddef>

// ---------------- types & helpers ----------------
typedef __attribute__((ext_vector_type(4))) float floatx4;
typedef __attribute__((ext_vector_type(8))) short short8;

__device__ __forceinline__ short f2bf(float x) {
  union { float f; unsigned u; } c; c.f = x;
  unsigned r = (c.u + 0x7FFFu + ((c.u >> 16) & 1u)) >> 16;  // RNE
  return (short)r;
}

__device__ __forceinline__ float bf2f(short x) {
  union { unsigned u; float f; } c; c.u = ((unsigned)(unsigned short)x) << 16;
  return c.f;
}

__device__ __forceinline__ floatx4 mfma16(short8 a, short8 b, floatx4 c) {
  return __builtin_amdgcn_mfma_f32_16x16x32_bf16(a, b, c, 0, 0, 0);
}

// async global->LDS, 16B per lane; LDS dest is wave-uniform base + lane*16
template <typename T>
__device__ __forceinline__ void gl_lds16(const T* g, T* l) {
  __builtin_amdgcn_global_load_lds(
      (__attribute__((address_space(1))) void*)g,
      (__attribute__((address_space(3))) void*)l, 16, 0, 0);
}

// ---------------- rmsnorm (+silu) with optional replicate-pad ----------------
template <bool PAD, bool SILU>
__global__ __launch_bounds__(256) void norm_kernel(const float* __restrict__ src,
                                                   const float* __restrict__ gamma,
                                                   short* __restrict__ dst) {
  const int tid = threadIdx.x;
  const int wv = tid >> 6, lane = tid & 63;
  const int id = blockIdx.x * 4 + wv;
  int srow;
  if (PAD) {
    int tp = id / 1156, rem = id - tp * 1156;
    int hp = rem / 34, wp = rem - hp * 34;
    int t = tp - 2; t = t < 0 ? 0 : t;
    int h = hp - 1; h = h < 0 ? 0 : (h > 31 ? 31 : h);
    int w = wp - 1; w = w < 0 ? 0 : (w > 31 ? 31 : w);
    srow = (t << 10) + (h << 5) + w;
  } else {
    srow = id;
  }
  const float* sp = src + (size_t)srow * 512 + lane * 8;
  float4 v0 = *(const float4*)sp;
  float4 v1 = *(const float4*)(sp + 4);
  float a[8] = {v0.x, v0.y, v0.z, v0.w, v1.x, v1.y, v1.z, v1.w};
  float ss = 0.f;
#pragma unroll
  for (int i = 0; i < 8; ++i) ss += a[i] * a[i];
#pragma unroll
  for (int off = 32; off > 0; off >>= 1) ss += __shfl_xor(ss, off);
  const float scale = 22.627416997969522f / (sqrtf(ss) + 1e-8f);  // sqrt(512)/(||x||+eps)
  const float* gp = gamma + lane * 8;
  float4 g0 = *(const float4*)gp;
  float4 g1 = *(const float4*)(gp + 4);
  float g[8] = {g0.x, g0.y, g0.z, g0.w, g1.x, g1.y, g1.z, g1.w};
  short8 ov;
#pragma unroll
  for (int i = 0; i < 8; ++i) {
    float y = a[i] * scale * g[i];
    if (SILU) y = y / (1.f + __expf(-y));
    ov[i] = f2bf(y);
  }
  *(short8*)(dst + (size_t)id * 512 + lane * 8) = ov;
}

// ---------------- weight transpose fp32 [R][C] -> bf16 [C][R] ----------------
__global__ __launch_bounds__(256) void transpose_w(const float* __restrict__ src,
                                                   short* __restrict__ dst, int R, int C) {
  __shared__ float t[32][33];
  const int tx = threadIdx.x & 31, ty = threadIdx.x >> 5;
  const int r0 = (int)blockIdx.x << 5, c0 = (int)blockIdx.y << 5;
#pragma unroll
  for (int i = 0; i < 4; ++i)
    t[ty + i * 8][tx] = src[(size_t)(r0 + ty + i * 8) * C + c0 + tx];
  __syncthreads();
#pragma unroll
  for (int i = 0; i < 4; ++i)
    dst[(size_t)(c0 + ty + i * 8) * R + r0 + tx] = f2bf(t[tx][ty + i * 8]);
}

// ---------------- implicit-GEMM causal conv3d, split-K 2-way ----------------
__global__ __launch_bounds__(256) void conv_gemm_sp(const short* __restrict__ Xp,
                                                    const short* __restrict__ WT,
                                                    float* __restrict__ P0,
                                                    float* __restrict__ P1) {
  __shared__ __attribute__((aligned(16))) short Alds[4096];
  __shared__ __attribute__((aligned(16))) short Blds[4096];
  const int tid = threadIdx.x;
  const int wv = tid >> 6, lane = tid & 63;
  const int m0 = (int)blockIdx.x << 7, n0 = (int)blockIdx.y << 7;
  const int z = blockIdx.z;
  float* __restrict__ dst = z ? P1 : P0;

  int aoff[2], boff[2];
#pragma unroll
  for (int j = 0; j < 2; ++j) {
    const int chunk = wv * 2 + j;
    const int m = m0 + chunk * 16 + (lane >> 2);
    const int t = m >> 10, h = (m >> 5) & 31, w = m & 31;
    aoff[j] = (t * 1156 + h * 34 + w) * 512 + (lane & 3) * 8;
    const int n = n0 + chunk * 16 + (lane >> 2);
    boff[j] = n * 13824 + (lane & 3) * 8;
  }
  const int wm = (wv & 1) << 6, wn = (wv >> 1) << 6;
  floatx4 acc[4][4];
#pragma unroll
  for (int i = 0; i < 4; ++i)
#pragma unroll
    for (int j = 0; j < 4; ++j) acc[i][j] = 0.f;

  const int la = (lane & 15) * 32 + (lane >> 4) * 8;
  const int k0 = z * 216;

  for (int kk = k0; kk < k0 + 216; ++kk) {
    const int tap = kk >> 4;
    const int cin0 = (kk & 15) << 5;
    const int dt = tap / 9;
    const int r9 = tap - dt * 9;
    const int dh = r9 / 3;
    const int dw = r9 - dh * 3;
    const int tapoff = (dt * 1156 + dh * 34 + dw) * 512 + cin0;
#pragma unroll
    for (int j = 0; j < 2; ++j) {
      const int chunk = wv * 2 + j;
      gl_lds16(Xp + aoff[j] + tapoff, &Alds[chunk * 512]);
      gl_lds16(WT + boff[j] + (kk << 5), &Blds[chunk * 512]);
    }
    __syncthreads();
    short8 af[4], bf[4];
#pragma unroll
    for (int i = 0; i < 4; ++i) af[i] = *(const short8*)&Alds[(wm + i * 16) * 32 + la];
#pragma unroll
    for (int j = 0; j < 4; ++j) bf[j] = *(const short8*)&Blds[(wn + j * 16) * 32 + la];
#pragma unroll
    for (int i = 0; i < 4; ++i)
#pragma unroll
      for (int j = 0; j < 4; ++j) acc[i][j] = mfma16(af[i], bf[j], acc[i][j]);
    __syncthreads();
  }

  const int rbase = m0 + wm + (lane >> 4) * 4;
#pragma unroll
  for (int i = 0; i < 4; ++i) {
    const int row = rbase + i * 16;
#pragma unroll
    for (int j = 0; j < 4; ++j) {
      const int col = n0 + wn + j * 16 + (lane & 15);
#pragma unroll
      for (int r = 0; r < 4; ++r)
        dst[(size_t)(row + r) * 512 + col] = acc[i][j][r];
    }
  }
}

template <bool HAS_RES>
__global__ __launch_bounds__(256) void conv_combine(const float* __restrict__ P0,
                                                    const float* __restrict__ P1,
                                                    const float* __restrict__ bias,
                                                    const float* __restrict__ res,
                                                    float* __restrict__ out) {
  const size_t i = ((size_t)blockIdx.x * 256 + threadIdx.x) * 4;
  float4 a = *(const float4*)(P0 + i);
  float4 b = *(const float4*)(P1 + i);
  float4 bz = *(const float4*)(bias + (int)(i & 511));
  float4 r;
  r.x = a.x + b.x + bz.x;
  r.y = a.y + b.y + bz.y;
  r.z = a.z + b.z + bz.z;
  r.w = a.w + b.w + bz.w;
  if (HAS_RES) {
    float4 rs = *(const float4*)(res + i);
    r.x += rs.x; r.y += rs.y; r.z += rs.z; r.w += rs.w;
  }
  *(float4*)(out + i) = r;
}

// ---------------- generic GEMM  C = A(MxK) * BT(NxK)^T ----------------
// EPI=0: QKV — Q row-major bf16; K,V written pre-swizzled per 32-key tile:
//   K tile offset(key,c) = (c>>5)*1024 + ((c>>3)&3)*256 + key*8 + (c&7)
//   V tile offset(key,c) = ((key>>3)&3)*4096 + c*8 + (key&7)
// EPI=1: fp32 out = acc + bias + res (proj + identity; in-place-safe).
template <int EPI>
__global__ __launch_bounds__(256) void gemm_bt(const short* __restrict__ A,
                                               const short* __restrict__ BT, int kdim,
                                               const float* __restrict__ b0,
                                               const float* __restrict__ b1,
                                               const float* __restrict__ b2,
                                               short* __restrict__ o0,
                                               short* __restrict__ o1,
                                               short* __restrict__ o2,
                                               float* oF, const float* res) {
  __shared__ __attribute__((aligned(16))) short Alds[4096];
  __shared__ __attribute__((aligned(16))) short Blds[4096];
  const int tid = threadIdx.x;
  const int wv = tid >> 6, lane = tid & 63;
  const int m0 = (int)blockIdx.x << 7, n0 = (int)blockIdx.y << 7;
  int aoff[2], boff[2];
#pragma unroll
  for (int j = 0; j < 2; ++j) {
    const int chunk = wv * 2 + j;
    aoff[j] = (m0 + chunk * 16 + (lane >> 2)) * kdim + (lane & 3) * 8;
    boff[j] = (n0 + chunk * 16 + (lane >> 2)) * kdim + (lane & 3) * 8;
  }
  const int wm = (wv & 1) << 6, wn = (wv >> 1) << 6;
  floatx4 acc[4][4];
#pragma unroll
  for (int i = 0; i < 4; ++i)
#pragma unroll
    for (int j = 0; j < 4; ++j) acc[i][j] = 0.f;
  const int la = (lane & 15) * 32 + (lane >> 4) * 8;
  const int kiters = kdim >> 5;

  for (int kk = 0; kk < kiters; ++kk) {
#pragma unroll
    for (int j = 0; j < 2; ++j) {
      const int chunk = wv * 2 + j;
      gl_lds16(A + aoff[j] + (kk << 5), &Alds[chunk * 512]);
      gl_lds16(BT + boff[j] + (kk << 5), &Blds[chunk * 512]);
    }
    __syncthreads();
    short8 af[4], bf[4];
#pragma unroll
    for (int i = 0; i < 4; ++i) af[i] = *(const short8*)&Alds[(wm + i * 16) * 32 + la];
#pragma unroll
    for (int j = 0; j < 4; ++j) bf[j] = *(const short8*)&Blds[(wn + j * 16) * 32 + la];
#pragma unroll
    for (int i = 0; i < 4; ++i)
#pragma unroll
      for (int j = 0; j < 4; ++j) acc[i][j] = mfma16(af[i], bf[j], acc[i][j]);
    __syncthreads();
  }

  const int rbase = m0 + wm + (lane >> 4) * 4;
#pragma unroll
  for (int i = 0; i < 4; ++i) {
    const int row = rbase + i * 16;
#pragma unroll
    for (int j = 0; j < 4; ++j) {
      const int col = n0 + wn + j * 16 + (lane & 15);
      if (EPI == 0) {
        const int sel = col >> 9;
        const int c = col & 511;
        const float* bp = sel == 0 ? b0 : (sel == 1 ? b1 : b2);
        const float bz = bp[c];
#pragma unroll
        for (int r = 0; r < 4; ++r) {
          const int rr = row + r;
          const short v = f2bf(acc[i][j][r] + bz);
          if (sel == 0) {
            o0[(size_t)rr * 512 + c] = v;
          } else if (sel == 1) {
            o1[(size_t)(rr >> 5) * 16384 + ((c >> 5) << 10) + (((c >> 3) & 3) << 8) +
               ((rr & 31) << 3) + (c & 7)] = v;
          } else {
            o2[(size_t)(rr >> 5) * 16384 + (((rr >> 3) & 3) << 12) + (c << 3) + (rr & 7)] = v;
          }
        }
      } else {
        const float bz = b0[col];
#pragma unroll
        for (int r = 0; r < 4; ++r) {
          const size_t idx = (size_t)(row + r) * 512 + col;
          oF[idx] = acc[i][j][r] + bz + res[idx];
        }
      }
    }
  }
}

// ---------------- split-K flash attention partials ----------------
// block = (64 q, one 1024-key frame chunk). 4 waves, each owns 16 q rows.
// K AND V staged to LDS once per 32-key tile (shared by all 4 waves; V was
// previously read per-wave from global = 4x traffic -> L3-bound).
// blockIdx swizzled so the 16 qb sharing a chunk land on one XCD (bid%8).
__global__ __launch_bounds__(256, 2) void attn_partial(const short* __restrict__ Q,
                                                       const short* __restrict__ Ksw,
                                                       const short* __restrict__ Vsw,
                                                       short* __restrict__ OpA,
                                                       short* __restrict__ OpB,
                                                       float* __restrict__ Mp,
                                                       float* __restrict__ Lp) {
  __shared__ __attribute__((aligned(16))) short Klds[16384];
  __shared__ __attribute__((aligned(16))) short Vlds[16384];
  __shared__ __attribute__((aligned(16))) short Plds[4][512];
  const int tid = threadIdx.x;
  const int wv = tid >> 6, lane = tid & 63;
  const int cl = lane & 15, quad = lane >> 4;
  // XCD-clustered mapping: xcd = bid & 7 (HW round-robin heuristic).
  const int bid = (int)blockIdx.x;
  const int x8 = bid & 7, jj = bid >> 3;
  int y, qb;
  if (jj < 64) {
    y = x8 + ((jj >> 4) << 3);   // y in {x8, x8+8, x8+16, x8+24}
    qb = jj & 15;
  } else {
    const int L = x8 * 8 + (jj - 64);  // leftover y = 32..35
    y = 32 + (L >> 4);
    qb = L & 15;
  }
  int f = 0;
  while ((f + 1) * (f + 2) / 2 <= y) ++f;
  const int chunk = y - f * (f + 1) / 2;
  const int pidx = y * 16 + qb;
  const int q0 = (f << 10) + (qb << 6);

  short8 qf[16];
  {
    const short* qp = Q + (size_t)(q0 + wv * 16 + cl) * 512 + quad * 8;
#pragma unroll
    for (int kc = 0; kc < 16; ++kc) qf[kc] = *(const short8*)(qp + kc * 32);
  }
  floatx4 o[32];
#pragma unroll
  for (int i = 0; i < 32; ++i) o[i] = 0.f;
  float mr[4] = {-1e30f, -1e30f, -1e30f, -1e30f};
  float lr[4] = {0.f, 0.f, 0.f, 0.f};
  const float c1 = 0.063758716f;  // log2(e)/sqrt(512)
  const short* klb = Klds + quad * 256 + cl * 8;
  const short* vlb = Vlds + quad * 4096 + cl * 8;
  const int swr = ((cl >> 1) & 3) << 3;

  for (int kt = 0; kt < 32; ++kt) {
    const size_t tb = (size_t)((chunk << 5) + kt) * 16384;
    const short* kg = Ksw + tb;
    const short* vg = Vsw + tb;
#pragma unroll
    for (int j = 0; j < 8; ++j) {
      const int row = (j * 4 + wv) << 9;
      gl_lds16(kg + row + lane * 8, &Klds[row]);
      gl_lds16(vg + row + lane * 8, &Vlds[row]);
    }
    __syncthreads();

    floatx4 s0 = 0.f, s1 = 0.f;
#pragma unroll
    for (int kc = 0; kc < 16; ++kc) {
      short8 k0 = *(const short8*)(klb + kc * 1024);
      short8 k1 = *(const short8*)(klb + kc * 1024 + 128);
      s0 = mfma16(qf[kc], k0, s0);
      s1 = mfma16(qf[kc], k1, s1);
    }

    float alpha[4];
#pragma unroll
    for (int r = 0; r < 4; ++r) {
      float a0 = s0[r] * c1, a1 = s1[r] * c1;
      float mx = fmaxf(a0, a1);
      mx = fmaxf(mx, __shfl_xor(mx, 1));
      mx = fmaxf(mx, __shfl_xor(mx, 2));
      mx = fmaxf(mx, __shfl_xor(mx, 4));
      mx = fmaxf(mx, __shfl_xor(mx, 8));
      const float mn = fmaxf(mr[r], mx);
      const float al = exp2f(mr[r] - mn);
      const float p0 = exp2f(a0 - mn), p1 = exp2f(a1 - mn);
      float ps = p0 + p1;
      ps += __shfl_xor(ps, 1);
      ps += __shfl_xor(ps, 2);
      ps += __shfl_xor(ps, 4);
      ps += __shfl_xor(ps, 8);
      lr[r] = lr[r] * al + ps;
      mr[r] = mn;
      alpha[r] = al;
      const int qlr = quad * 4 + r;
      const int sw = ((qlr >> 1) & 3) << 3;
      const int oi = qlr * 32 + (cl ^ sw);
      Plds[wv][oi] = f2bf(p0);
      Plds[wv][oi ^ 16] = f2bf(p1);
    }
    const short8 pf = *(const short8*)&Plds[wv][cl * 32 + ((quad << 3) ^ swr)];
#pragma unroll
    for (int cn = 0; cn < 32; ++cn) {
      const short8 vf = *(const short8*)(vlb + cn * 128);
      floatx4 t = o[cn];
      t[0] *= alpha[0];
      t[1] *= alpha[1];
      t[2] *= alpha[2];
      t[3] *= alpha[3];
      o[cn] = mfma16(pf, vf, t);
    }
    __syncthreads();
  }

  short* base = pidx < 216 ? OpA + (size_t)pidx * 32768 : OpB + (size_t)(pidx - 216) * 32768;
  const int lrow0 = wv * 16 + quad * 4;
#pragma unroll
  for (int cn = 0; cn < 32; ++cn) {
    const int col = cn * 16 + cl;
#pragma unroll
    for (int r = 0; r < 4; ++r)
      base[(size_t)(lrow0 + r) * 512 + col] = f2bf(o[cn][r]);
  }
  if (cl == 0) {
#pragma unroll
    for (int r = 0; r < 4; ++r) {
      Mp[pidx * 64 + lrow0 + r] = mr[r];
      Lp[pidx * 64 + lrow0 + r] = lr[r];
    }
  }
}

// ---------------- attention combine: merge up to 8 chunk partials ----------------
__global__ __launch_bounds__(256) void attn_combine(const short* __restrict__ OpA,
                                                    const short* __restrict__ OpB,
                                                    const float* __restrict__ Mp,
                                                    const float* __restrict__ Lp,
                                                    short* __restrict__ O) {
  const int tid = threadIdx.x;
  const int wv = tid >> 6, lane = tid & 63;
  const int row = (int)blockIdx.x * 4 + wv;
  const int f = row >> 10, n = f + 1;
  const int qb = (row >> 6) & 15, lrow = row & 63;
  const int tri = f * (f + 1) / 2;
  float mv[8], lv[8];
#pragma unroll
  for (int ch = 0; ch < 8; ++ch) {
    if (ch < n) {
      const int pidx = (tri + ch) * 16 + qb;
      mv[ch] = Mp[pidx * 64 + lrow];
      lv[ch] = Lp[pidx * 64 + lrow];
    } else {
      mv[ch] = -1e30f;
      lv[ch] = 0.f;
    }
  }
  float M = mv[0];
#pragma unroll
  for (int ch = 1; ch < 8; ++ch) M = fmaxf(M, mv[ch]);
  float den = 0.f, acc[8];
#pragma unroll
  for (int i = 0; i < 8; ++i) acc[i] = 0.f;
#pragma unroll
  for (int ch = 0; ch < 8; ++ch) {
    if (ch < n) {
      const float w = exp2f(mv[ch] - M);
      den += w * lv[ch];
      const int pidx = (tri + ch) * 16 + qb;
      const short* b = pidx < 216 ? OpA + (size_t)pidx * 32768 : OpB + (size_t)(pidx - 216) * 32768;
      const short8 v = *(const short8*)(b + (size_t)lrow * 512 + lane * 8);
#pragma unroll
      for (int i = 0; i < 8; ++i) acc[i] += w * bf2f(v[i]);
    }
  }
  const float inv = 1.f / den;
  short8 ov;
#pragma unroll
  for (int i = 0; i < 8; ++i) ov[i] = f2bf(acc[i] * inv);
  *(short8*)(O + (size_t)row * 512 + lane * 8) = ov;
}

// ---------------- host ----------------
extern "C" void kernel_launch(void* const* d_in, const int* in_sizes, int n_in,
                              void* d_out, int out_size, void* d_ws, size_t ws_size,
                              hipStream_t stream) {
  const float* x     = (const float*)d_in[0];
  const float* r1_g1 = (const float*)d_in[1];
  const float* r1_w1 = (const float*)d_in[2];
  const float* r1_b1 = (const float*)d_in[3];
  const float* r1_g2 = (const float*)d_in[4];
  const float* r1_w2 = (const float*)d_in[5];
  const float* r1_b2 = (const float*)d_in[6];
  const float* at_g  = (const float*)d_in[7];
  const float* q_w   = (const float*)d_in[8];
  const float* q_b   = (const float*)d_in[9];
  const float* k_w   = (const float*)d_in[10];
  const float* k_b   = (const float*)d_in[11];
  const float* v_w   = (const float*)d_in[12];
  const float* v_b   = (const float*)d_in[13];
  const float* p_w   = (const float*)d_in[14];
  const float* p_b   = (const float*)d_in[15];
  const float* r2_g1 = (const float*)d_in[16];
  const float* r2_w1 = (const float*)d_in[17];
  const float* r2_b1 = (const float*)d_in[18];
  const float* r2_g2 = (const float*)d_in[19];
  const float* r2_w2 = (const float*)d_in[20];
  const float* r2_b2 = (const float*)d_in[21];
  float* out = (float*)d_out;

  char* ws = (char*)d_ws;
  size_t off = 0;
  auto alloc = [&](size_t bytes) -> void* {
    void* p = ws + off;
    off = (off + bytes + 255) & ~(size_t)255;
    return p;
  };
  short* wT    = (short*)alloc(27ull * 512 * 512 * 2);      // 14.15 MB = 216 x 64KB partials
  short* wqkvT = (short*)alloc(1536ull * 512 * 2);
  short* pwT   = (short*)alloc(512ull * 512 * 2);
  short* Xp    = (short*)alloc(10ull * 34 * 34 * 512 * 2);  // padded act; +Y = partial region B
  float* Y     = (float*)alloc(8192ull * 512 * 4);
  float* hA    = (float*)alloc(8192ull * 512 * 4);
  short* xn    = (short*)alloc(8192ull * 512 * 2);          // + Qb = conv partial P0 (fp32)
  short* Qb    = (short*)alloc(8192ull * 512 * 2);
  short* Ksw   = (short*)alloc(8192ull * 512 * 2);          // + Vsw = conv partial P1 (fp32)
  short* Vsw   = (short*)alloc(8192ull * 512 * 2);
  float* Mp    = (float*)alloc(576ull * 64 * 4);
  float* Lp    = (float*)alloc(576ull * 64 * 4);
  (void)ws_size; (void)in_sizes; (void)n_in; (void)out_size;

  short* OpA = wT;          // 216 partials
  short* OpB = Xp;          // 360 partials (Xp+Y contiguous = 436 capacity)
  float* P0  = (float*)xn;  // xn+Qb contiguous = 16.78 MB fp32
  float* P1  = (float*)Ksw; // Ksw+Vsw contiguous

  const dim3 b256(256);
  const dim3 convg(64, 4, 2);

  // ----- resnet 1 -----
  transpose_w<<<dim3(432, 16), b256, 0, stream>>>(r1_w1, wT, 13824, 512);
  norm_kernel<true, true><<<2890, b256, 0, stream>>>(x, r1_g1, Xp);
  conv_gemm_sp<<<convg, b256, 0, stream>>>(Xp, wT, P0, P1);
  conv_combine<false><<<4096, b256, 0, stream>>>(P0, P1, r1_b1, nullptr, Y);
  transpose_w<<<dim3(432, 16), b256, 0, stream>>>(r1_w2, wT, 13824, 512);
  norm_kernel<true, true><<<2890, b256, 0, stream>>>(Y, r1_g2, Xp);
  conv_gemm_sp<<<convg, b256, 0, stream>>>(Xp, wT, P0, P1);
  conv_combine<true><<<4096, b256, 0, stream>>>(P0, P1, r1_b2, x, hA);

  // ----- attention -----
  norm_kernel<false, false><<<2048, b256, 0, stream>>>(hA, at_g, xn);
  transpose_w<<<dim3(16, 16), b256, 0, stream>>>(q_w, wqkvT, 512, 512);
  transpose_w<<<dim3(16, 16), b256, 0, stream>>>(k_w, wqkvT + 512 * 512, 512, 512);
  transpose_w<<<dim3(16, 16), b256, 0, stream>>>(v_w, wqkvT + 1024 * 512, 512, 512);
  transpose_w<<<dim3(16, 16), b256, 0, stream>>>(p_w, pwT, 512, 512);
  gemm_bt<0><<<dim3(64, 12), b256, 0, stream>>>(xn, wqkvT, 512, q_b, k_b, v_b,
                                                Qb, Ksw, Vsw, nullptr, nullptr);
  attn_partial<<<576, b256, 0, stream>>>(Qb, Ksw, Vsw, OpA, OpB, Mp, Lp);
  attn_combine<<<2048, b256, 0, stream>>>(OpA, OpB, Mp, Lp, xn);
  gemm_bt<1><<<dim3(64, 4), b256, 0, stream>>>(xn, pwT, 512, p_b, nullptr, nullptr,
                                               nullptr, nullptr, nullptr, hA, hA);

  // ----- resnet 2 -----
  transpose_w<<<dim3(432, 16), b256, 0, stream>>>(r2_w1, wT, 13824, 512);
  norm_kernel<true, true><<<2890, b256, 0, stream>>>(hA, r2_g1, Xp);
  conv_gemm_sp<<<convg, b256, 0, stream>>>(Xp, wT, P0, P1);
  conv_combine<false><<<4096, b256, 0, stream>>>(P0, P1, r2_b1, nullptr, Y);
  transpose_w<<<dim3(432, 16), b256, 0, stream>>>(r2_w2, wT, 13824, 512);
  norm_kernel<true, true><<<2890, b256, 0, stream>>>(Y, r2_g2, Xp);
  conv_gemm_sp<<<convg, b256, 0, stream>>>(Xp, wT, P0, P1);
  conv_combine<true><<<4096, b256, 0, stream>>>(P0, P1, r2_b2, hA, out);
}

// Round 4
// 1126.287 us; speedup vs baseline: 2.1771x; 1.1619x over previous
//
#include <hip/hip_runtime.h>
#include <cstdint>
#include <cstddef>

// ---------------- types & helpers ----------------
typedef __attribute__((ext_vector_type(4))) float floatx4;
typedef __attribute__((ext_vector_type(8))) short short8;

__device__ __forceinline__ short f2bf(float x) {
  union { float f; unsigned u; } c; c.f = x;
  unsigned r = (c.u + 0x7FFFu + ((c.u >> 16) & 1u)) >> 16;  // RNE
  return (short)r;
}

__device__ __forceinline__ float bf2f(short x) {
  union { unsigned u; float f; } c; c.u = ((unsigned)(unsigned short)x) << 16;
  return c.f;
}

__device__ __forceinline__ floatx4 mfma16(short8 a, short8 b, floatx4 c) {
  return __builtin_amdgcn_mfma_f32_16x16x32_bf16(a, b, c, 0, 0, 0);
}

// async global->LDS, 16B per lane; LDS dest is wave-uniform base + lane*16
template <typename T>
__device__ __forceinline__ void gl_lds16(const T* g, T* l) {
  __builtin_amdgcn_global_load_lds(
      (__attribute__((address_space(1))) void*)g,
      (__attribute__((address_space(3))) void*)l, 16, 0, 0);
}

// ---------------- rmsnorm (+silu) with optional replicate-pad ----------------
template <bool PAD, bool SILU>
__global__ __launch_bounds__(256) void norm_kernel(const float* __restrict__ src,
                                                   const float* __restrict__ gamma,
                                                   short* __restrict__ dst) {
  const int tid = threadIdx.x;
  const int wv = tid >> 6, lane = tid & 63;
  const int id = blockIdx.x * 4 + wv;
  int srow;
  if (PAD) {
    int tp = id / 1156, rem = id - tp * 1156;
    int hp = rem / 34, wp = rem - hp * 34;
    int t = tp - 2; t = t < 0 ? 0 : t;
    int h = hp - 1; h = h < 0 ? 0 : (h > 31 ? 31 : h);
    int w = wp - 1; w = w < 0 ? 0 : (w > 31 ? 31 : w);
    srow = (t << 10) + (h << 5) + w;
  } else {
    srow = id;
  }
  const float* sp = src + (size_t)srow * 512 + lane * 8;
  float4 v0 = *(const float4*)sp;
  float4 v1 = *(const float4*)(sp + 4);
  float a[8] = {v0.x, v0.y, v0.z, v0.w, v1.x, v1.y, v1.z, v1.w};
  float ss = 0.f;
#pragma unroll
  for (int i = 0; i < 8; ++i) ss += a[i] * a[i];
#pragma unroll
  for (int off = 32; off > 0; off >>= 1) ss += __shfl_xor(ss, off);
  const float scale = 22.627416997969522f / (sqrtf(ss) + 1e-8f);  // sqrt(512)/(||x||+eps)
  const float* gp = gamma + lane * 8;
  float4 g0 = *(const float4*)gp;
  float4 g1 = *(const float4*)(gp + 4);
  float g[8] = {g0.x, g0.y, g0.z, g0.w, g1.x, g1.y, g1.z, g1.w};
  short8 ov;
#pragma unroll
  for (int i = 0; i < 8; ++i) {
    float y = a[i] * scale * g[i];
    if (SILU) y = y / (1.f + __expf(-y));
    ov[i] = f2bf(y);
  }
  *(short8*)(dst + (size_t)id * 512 + lane * 8) = ov;
}

// ---------------- fused split-K combine + rmsnorm + silu + replicate-pad ----------------
// y = P0 + P1 + bias; out = silu(rmsnorm(y)*gamma) edge-padded to [10][34][34][512] bf16
__global__ __launch_bounds__(256) void combine_norm(const float* __restrict__ P0,
                                                    const float* __restrict__ P1,
                                                    const float* __restrict__ bias,
                                                    const float* __restrict__ gamma,
                                                    short* __restrict__ dst) {
  const int tid = threadIdx.x;
  const int wv = tid >> 6, lane = tid & 63;
  const int id = blockIdx.x * 4 + wv;
  int tp = id / 1156, rem = id - tp * 1156;
  int hp = rem / 34, wp = rem - hp * 34;
  int t = tp - 2; t = t < 0 ? 0 : t;
  int h = hp - 1; h = h < 0 ? 0 : (h > 31 ? 31 : h);
  int w = wp - 1; w = w < 0 ? 0 : (w > 31 ? 31 : w);
  const int srow = (t << 10) + (h << 5) + w;
  const float* sp0 = P0 + (size_t)srow * 512 + lane * 8;
  const float* sp1 = P1 + (size_t)srow * 512 + lane * 8;
  float4 a0 = *(const float4*)sp0, a1 = *(const float4*)(sp0 + 4);
  float4 b0 = *(const float4*)sp1, b1 = *(const float4*)(sp1 + 4);
  float4 z0 = *(const float4*)(bias + lane * 8), z1 = *(const float4*)(bias + lane * 8 + 4);
  float a[8] = {a0.x + b0.x + z0.x, a0.y + b0.y + z0.y, a0.z + b0.z + z0.z, a0.w + b0.w + z0.w,
                a1.x + b1.x + z1.x, a1.y + b1.y + z1.y, a1.z + b1.z + z1.z, a1.w + b1.w + z1.w};
  float ss = 0.f;
#pragma unroll
  for (int i = 0; i < 8; ++i) ss += a[i] * a[i];
#pragma unroll
  for (int off = 32; off > 0; off >>= 1) ss += __shfl_xor(ss, off);
  const float scale = 22.627416997969522f / (sqrtf(ss) + 1e-8f);
  float4 g0 = *(const float4*)(gamma + lane * 8), g1 = *(const float4*)(gamma + lane * 8 + 4);
  float g[8] = {g0.x, g0.y, g0.z, g0.w, g1.x, g1.y, g1.z, g1.w};
  short8 ov;
#pragma unroll
  for (int i = 0; i < 8; ++i) {
    float y = a[i] * scale * g[i];
    y = y / (1.f + __expf(-y));
    ov[i] = f2bf(y);
  }
  *(short8*)(dst + (size_t)id * 512 + lane * 8) = ov;
}

// ---------------- weight transpose fp32 [R][C] -> bf16 [C][R] ----------------
__global__ __launch_bounds__(256) void transpose_w(const float* __restrict__ src,
                                                   short* __restrict__ dst, int R, int C) {
  __shared__ float t[32][33];
  const int tx = threadIdx.x & 31, ty = threadIdx.x >> 5;
  const int r0 = (int)blockIdx.x << 5, c0 = (int)blockIdx.y << 5;
#pragma unroll
  for (int i = 0; i < 4; ++i)
    t[ty + i * 8][tx] = src[(size_t)(r0 + ty + i * 8) * C + c0 + tx];
  __syncthreads();
#pragma unroll
  for (int i = 0; i < 4; ++i)
    dst[(size_t)(c0 + ty + i * 8) * R + r0 + tx] = f2bf(t[tx][ty + i * 8]);
}

// ---------------- implicit-GEMM causal conv3d, split-K 2-way, dbuf prefetch ----------------
__global__ __launch_bounds__(256) void conv_gemm_sp(const short* __restrict__ Xp,
                                                    const short* __restrict__ WT,
                                                    float* __restrict__ P0,
                                                    float* __restrict__ P1) {
  __shared__ __attribute__((aligned(16))) short Alds[2][4096];
  __shared__ __attribute__((aligned(16))) short Blds[2][4096];
  const int tid = threadIdx.x;
  const int wv = tid >> 6, lane = tid & 63;
  const int m0 = (int)blockIdx.x << 7, n0 = (int)blockIdx.y << 7;
  const int z = blockIdx.z;
  float* __restrict__ dst = z ? P1 : P0;

  int aoff[2], boff[2];
#pragma unroll
  for (int j = 0; j < 2; ++j) {
    const int chunk = wv * 2 + j;
    const int m = m0 + chunk * 16 + (lane >> 2);
    const int t = m >> 10, h = (m >> 5) & 31, w = m & 31;
    aoff[j] = (t * 1156 + h * 34 + w) * 512 + (lane & 3) * 8;
    const int n = n0 + chunk * 16 + (lane >> 2);
    boff[j] = n * 13824 + (lane & 3) * 8;
  }
  const int wm = (wv & 1) << 6, wn = (wv >> 1) << 6;
  floatx4 acc[4][4];
#pragma unroll
  for (int i = 0; i < 4; ++i)
#pragma unroll
    for (int j = 0; j < 4; ++j) acc[i][j] = 0.f;

  const int la = (lane & 15) * 32 + (lane >> 4) * 8;
  const int k0 = z * 216, k1 = k0 + 216;

  auto stage = [&](int kk, int buf) {
    const int tap = kk >> 4;
    const int cin0 = (kk & 15) << 5;
    const int dt = tap / 9;
    const int r9 = tap - dt * 9;
    const int dh = r9 / 3;
    const int dw = r9 - dh * 3;
    const int tapoff = (dt * 1156 + dh * 34 + dw) * 512 + cin0;
#pragma unroll
    for (int j = 0; j < 2; ++j) {
      const int chunk = wv * 2 + j;
      gl_lds16(Xp + aoff[j] + tapoff, &Alds[buf][chunk * 512]);
      gl_lds16(WT + boff[j] + (kk << 5), &Blds[buf][chunk * 512]);
    }
  };

  stage(k0, 0);
  for (int kk = k0; kk < k1; ++kk) {
    const int cur = (kk - k0) & 1;
    __syncthreads();
    if (kk + 1 < k1) stage(kk + 1, cur ^ 1);
    short8 af[4], bf[4];
#pragma unroll
    for (int i = 0; i < 4; ++i) af[i] = *(const short8*)&Alds[cur][(wm + i * 16) * 32 + la];
#pragma unroll
    for (int j = 0; j < 4; ++j) bf[j] = *(const short8*)&Blds[cur][(wn + j * 16) * 32 + la];
#pragma unroll
    for (int i = 0; i < 4; ++i)
#pragma unroll
      for (int j = 0; j < 4; ++j) acc[i][j] = mfma16(af[i], bf[j], acc[i][j]);
  }

  const int rbase = m0 + wm + (lane >> 4) * 4;
#pragma unroll
  for (int i = 0; i < 4; ++i) {
    const int row = rbase + i * 16;
#pragma unroll
    for (int j = 0; j < 4; ++j) {
      const int col = n0 + wn + j * 16 + (lane & 15);
#pragma unroll
      for (int r = 0; r < 4; ++r)
        dst[(size_t)(row + r) * 512 + col] = acc[i][j][r];
    }
  }
}

template <bool HAS_RES>
__global__ __launch_bounds__(256) void conv_combine(const float* __restrict__ P0,
                                                    const float* __restrict__ P1,
                                                    const float* __restrict__ bias,
                                                    const float* __restrict__ res,
                                                    float* __restrict__ out) {
  const size_t i = ((size_t)blockIdx.x * 256 + threadIdx.x) * 4;
  float4 a = *(const float4*)(P0 + i);
  float4 b = *(const float4*)(P1 + i);
  float4 bz = *(const float4*)(bias + (int)(i & 511));
  float4 r;
  r.x = a.x + b.x + bz.x;
  r.y = a.y + b.y + bz.y;
  r.z = a.z + b.z + bz.z;
  r.w = a.w + b.w + bz.w;
  if (HAS_RES) {
    float4 rs = *(const float4*)(res + i);
    r.x += rs.x; r.y += rs.y; r.z += rs.z; r.w += rs.w;
  }
  *(float4*)(out + i) = r;
}

// ---------------- generic GEMM  C = A(MxK) * BT(NxK)^T, dbuf prefetch ----------------
// EPI=0: QKV — Q row-major bf16; K,V written pre-swizzled per 32-key tile:
//   K tile offset(key,c) = (c>>5)*1024 + ((c>>3)&3)*256 + key*8 + (c&7)
//   V tile offset(key,c) = ((key>>3)&3)*4096 + c*8 + (key&7)
// EPI=1: fp32 out = acc + bias + res (proj + identity; in-place-safe).
template <int EPI>
__global__ __launch_bounds__(256) void gemm_bt(const short* __restrict__ A,
                                               const short* __restrict__ BT, int kdim,
                                               const float* __restrict__ b0,
                                               const float* __restrict__ b1,
                                               const float* __restrict__ b2,
                                               short* __restrict__ o0,
                                               short* __restrict__ o1,
                                               short* __restrict__ o2,
                                               float* oF, const float* res) {
  __shared__ __attribute__((aligned(16))) short Alds[2][4096];
  __shared__ __attribute__((aligned(16))) short Blds[2][4096];
  const int tid = threadIdx.x;
  const int wv = tid >> 6, lane = tid & 63;
  const int m0 = (int)blockIdx.x << 7, n0 = (int)blockIdx.y << 7;
  int aoff[2], boff[2];
#pragma unroll
  for (int j = 0; j < 2; ++j) {
    const int chunk = wv * 2 + j;
    aoff[j] = (m0 + chunk * 16 + (lane >> 2)) * kdim + (lane & 3) * 8;
    boff[j] = (n0 + chunk * 16 + (lane >> 2)) * kdim + (lane & 3) * 8;
  }
  const int wm = (wv & 1) << 6, wn = (wv >> 1) << 6;
  floatx4 acc[4][4];
#pragma unroll
  for (int i = 0; i < 4; ++i)
#pragma unroll
    for (int j = 0; j < 4; ++j) acc[i][j] = 0.f;
  const int la = (lane & 15) * 32 + (lane >> 4) * 8;
  const int kiters = kdim >> 5;

  auto stage = [&](int kk, int buf) {
#pragma unroll
    for (int j = 0; j < 2; ++j) {
      const int chunk = wv * 2 + j;
      gl_lds16(A + aoff[j] + (kk << 5), &Alds[buf][chunk * 512]);
      gl_lds16(BT + boff[j] + (kk << 5), &Blds[buf][chunk * 512]);
    }
  };

  stage(0, 0);
  for (int kk = 0; kk < kiters; ++kk) {
    const int cur = kk & 1;
    __syncthreads();
    if (kk + 1 < kiters) stage(kk + 1, cur ^ 1);
    short8 af[4], bf[4];
#pragma unroll
    for (int i = 0; i < 4; ++i) af[i] = *(const short8*)&Alds[cur][(wm + i * 16) * 32 + la];
#pragma unroll
    for (int j = 0; j < 4; ++j) bf[j] = *(const short8*)&Blds[cur][(wn + j * 16) * 32 + la];
#pragma unroll
    for (int i = 0; i < 4; ++i)
#pragma unroll
      for (int j = 0; j < 4; ++j) acc[i][j] = mfma16(af[i], bf[j], acc[i][j]);
  }

  const int rbase = m0 + wm + (lane >> 4) * 4;
#pragma unroll
  for (int i = 0; i < 4; ++i) {
    const int row = rbase + i * 16;
#pragma unroll
    for (int j = 0; j < 4; ++j) {
      const int col = n0 + wn + j * 16 + (lane & 15);
      if (EPI == 0) {
        const int sel = col >> 9;
        const int c = col & 511;
        const float* bp = sel == 0 ? b0 : (sel == 1 ? b1 : b2);
        const float bz = bp[c];
#pragma unroll
        for (int r = 0; r < 4; ++r) {
          const int rr = row + r;
          const short v = f2bf(acc[i][j][r] + bz);
          if (sel == 0) {
            o0[(size_t)rr * 512 + c] = v;
          } else if (sel == 1) {
            o1[(size_t)(rr >> 5) * 16384 + ((c >> 5) << 10) + (((c >> 3) & 3) << 8) +
               ((rr & 31) << 3) + (c & 7)] = v;
          } else {
            o2[(size_t)(rr >> 5) * 16384 + (((rr >> 3) & 3) << 12) + (c << 3) + (rr & 7)] = v;
          }
        }
      } else {
        const float bz = b0[col];
#pragma unroll
        for (int r = 0; r < 4; ++r) {
          const size_t idx = (size_t)(row + r) * 512 + col;
          oF[idx] = acc[i][j][r] + bz + res[idx];
        }
      }
    }
  }
}

// ---------------- split-K flash attention partials ----------------
// block = 512 thr (8 waves) = 128 q x one 1024-key chunk; K+V double-buffered
// in LDS (one barrier/tile, prefetch overlaps MFMA); fixed-max softmax (m=0:
// scores bounded, exp2 cannot overflow) -> no max shuffles, no o-rescale.
__global__ __launch_bounds__(512, 2) void attn_partial(const short* __restrict__ Q,
                                                       const short* __restrict__ Ksw,
                                                       const short* __restrict__ Vsw,
                                                       short* __restrict__ OpA,
                                                       short* __restrict__ OpB,
                                                       float* __restrict__ Lp) {
  __shared__ __attribute__((aligned(16))) short Kl[2][16384];
  __shared__ __attribute__((aligned(16))) short Vl[2][16384];
  __shared__ __attribute__((aligned(16))) short Plds[8][512];
  const int tid = threadIdx.x;
  const int wv = tid >> 6, lane = tid & 63;
  const int cl = lane & 15, quad = lane >> 4;
  // XCD-clustered mapping: unit u = y*2+h (4 qb per unit) -> xcd = bid&7 = u&7
  const int bid = (int)blockIdx.x;
  const int u = ((bid >> 5) << 3) | (bid & 7);
  const int w4 = (bid >> 3) & 3;
  const int y = u >> 1;
  const int qb = ((u & 1) << 2) | w4;
  int f = 0;
  while ((f + 1) * (f + 2) / 2 <= y) ++f;
  const int chunk = y - f * (f + 1) / 2;
  const int pidx = y * 8 + qb;
  const int q0 = (f << 10) + (qb << 7);

  short8 qf[16];
  {
    const short* qp = Q + (size_t)(q0 + wv * 16 + cl) * 512 + quad * 8;
#pragma unroll
    for (int kc = 0; kc < 16; ++kc) qf[kc] = *(const short8*)(qp + kc * 32);
  }
  floatx4 o[32];
#pragma unroll
  for (int i = 0; i < 32; ++i) o[i] = 0.f;
  float lr[4] = {0.f, 0.f, 0.f, 0.f};
  const float c1 = 0.063758716f;  // log2(e)/sqrt(512)
  const int swr = ((cl >> 1) & 3) << 3;

  auto stage = [&](int kt, int buf) {
    const size_t tb = (size_t)((chunk << 5) + kt) * 16384;
    const short* kg = Ksw + tb + (wv << 11);
    const short* vg = Vsw + tb + (wv << 11);
    short* kl = &Kl[buf][wv << 11];
    short* vl = &Vl[buf][wv << 11];
#pragma unroll
    for (int i = 0; i < 4; ++i) {
      gl_lds16(kg + (i << 9) + lane * 8, kl + (i << 9));
      gl_lds16(vg + (i << 9) + lane * 8, vl + (i << 9));
    }
  };

  stage(0, 0);
  for (int kt = 0; kt < 32; ++kt) {
    const int cur = kt & 1;
    __syncthreads();
    if (kt + 1 < 32) stage(kt + 1, cur ^ 1);

    const short* klb = &Kl[cur][quad * 256 + cl * 8];
    floatx4 s0 = 0.f, s1 = 0.f;
#pragma unroll
    for (int kc = 0; kc < 16; ++kc) {
      short8 k0 = *(const short8*)(klb + kc * 1024);
      short8 k1 = *(const short8*)(klb + kc * 1024 + 128);
      s0 = mfma16(qf[kc], k0, s0);
      s1 = mfma16(qf[kc], k1, s1);
    }

#pragma unroll
    for (int r = 0; r < 4; ++r) {
      const float p0 = exp2f(s0[r] * c1), p1 = exp2f(s1[r] * c1);
      float ps = p0 + p1;
      ps += __shfl_xor(ps, 1);
      ps += __shfl_xor(ps, 2);
      ps += __shfl_xor(ps, 4);
      ps += __shfl_xor(ps, 8);
      lr[r] += ps;
      const int qlr = quad * 4 + r;
      const int sw = ((qlr >> 1) & 3) << 3;
      const int oi = qlr * 32 + (cl ^ sw);
      Plds[wv][oi] = f2bf(p0);
      Plds[wv][oi ^ 16] = f2bf(p1);
    }
    const short8 pf = *(const short8*)&Plds[wv][cl * 32 + ((quad << 3) ^ swr)];
    const short* vlb = &Vl[cur][quad * 4096 + cl * 8];
#pragma unroll
    for (int cn = 0; cn < 32; ++cn) {
      const short8 vf = *(const short8*)(vlb + cn * 128);
      o[cn] = mfma16(pf, vf, o[cn]);
    }
  }

  short* base = pidx < 108 ? OpA + (size_t)pidx * 65536 : OpB + (size_t)(pidx - 108) * 65536;
  const int lrow0 = wv * 16 + quad * 4;
#pragma unroll
  for (int cn = 0; cn < 32; ++cn) {
    const int col = cn * 16 + cl;
#pragma unroll
    for (int r = 0; r < 4; ++r)
      base[(size_t)(lrow0 + r) * 512 + col] = f2bf(o[cn][r]);
  }
  if (cl == 0) {
#pragma unroll
    for (int r = 0; r < 4; ++r) Lp[pidx * 128 + lrow0 + r] = lr[r];
  }
}

// ---------------- attention combine: merge up to 8 chunk partials ----------------
__global__ __launch_bounds__(256) void attn_combine(const short* __restrict__ OpA,
                                                    const short* __restrict__ OpB,
                                                    const float* __restrict__ Lp,
                                                    short* __restrict__ O) {
  const int tid = threadIdx.x;
  const int wv = tid >> 6, lane = tid & 63;
  const int row = (int)blockIdx.x * 4 + wv;
  const int f = row >> 10, n = f + 1;
  const int qb = (row >> 7) & 7, lrow = row & 127;
  const int tri = f * (f + 1) / 2;
  float den = 0.f, acc[8];
#pragma unroll
  for (int i = 0; i < 8; ++i) acc[i] = 0.f;
#pragma unroll
  for (int ch = 0; ch < 8; ++ch) {
    if (ch < n) {
      const int pidx = (tri + ch) * 8 + qb;
      den += Lp[pidx * 128 + lrow];
      const short* b = pidx < 108 ? OpA + (size_t)pidx * 65536 : OpB + (size_t)(pidx - 108) * 65536;
      const short8 v = *(const short8*)(b + (size_t)lrow * 512 + lane * 8);
#pragma unroll
      for (int i = 0; i < 8; ++i) acc[i] += bf2f(v[i]);
    }
  }
  const float inv = 1.f / den;
  short8 ov;
#pragma unroll
  for (int i = 0; i < 8; ++i) ov[i] = f2bf(acc[i] * inv);
  *(short8*)(O + (size_t)row * 512 + lane * 8) = ov;
}

// ---------------- host ----------------
extern "C" void kernel_launch(void* const* d_in, const int* in_sizes, int n_in,
                              void* d_out, int out_size, void* d_ws, size_t ws_size,
                              hipStream_t stream) {
  const float* x     = (const float*)d_in[0];
  const float* r1_g1 = (const float*)d_in[1];
  const float* r1_w1 = (const float*)d_in[2];
  const float* r1_b1 = (const float*)d_in[3];
  const float* r1_g2 = (const float*)d_in[4];
  const float* r1_w2 = (const float*)d_in[5];
  const float* r1_b2 = (const float*)d_in[6];
  const float* at_g  = (const float*)d_in[7];
  const float* q_w   = (const float*)d_in[8];
  const float* q_b   = (const float*)d_in[9];
  const float* k_w   = (const float*)d_in[10];
  const float* k_b   = (const float*)d_in[11];
  const float* v_w   = (const float*)d_in[12];
  const float* v_b   = (const float*)d_in[13];
  const float* p_w   = (const float*)d_in[14];
  const float* p_b   = (const float*)d_in[15];
  const float* r2_g1 = (const float*)d_in[16];
  const float* r2_w1 = (const float*)d_in[17];
  const float* r2_b1 = (const float*)d_in[18];
  const float* r2_g2 = (const float*)d_in[19];
  const float* r2_w2 = (const float*)d_in[20];
  const float* r2_b2 = (const float*)d_in[21];
  float* out = (float*)d_out;

  char* ws = (char*)d_ws;
  size_t off = 0;
  auto alloc = [&](size_t bytes) -> void* {
    void* p = ws + off;
    off = (off + bytes + 255) & ~(size_t)255;
    return p;
  };
  short* wT    = (short*)alloc(27ull * 512 * 512 * 2);      // 14.16 MB = 108 x 128KB attn partials
  short* wqkvT = (short*)alloc(1536ull * 512 * 2);
  short* pwT   = (short*)alloc(512ull * 512 * 2);
  short* Xp    = (short*)alloc(10ull * 34 * 34 * 512 * 2);  // padded act; Xp+Y = 180 partials
  float* Y     = (float*)alloc(8192ull * 512 * 4);
  float* hA    = (float*)alloc(8192ull * 512 * 4);
  short* xn    = (short*)alloc(8192ull * 512 * 2);          // + Qb = conv partial P0 (fp32)
  short* Qb    = (short*)alloc(8192ull * 512 * 2);
  short* Ksw   = (short*)alloc(8192ull * 512 * 2);          // + Vsw = conv partial P1 (fp32)
  short* Vsw   = (short*)alloc(8192ull * 512 * 2);
  float* Lp    = (float*)alloc(288ull * 128 * 4);
  (void)ws_size; (void)in_sizes; (void)n_in; (void)out_size; (void)Y;

  short* OpA = wT;          // 108 partials of 128q x 512c bf16
  short* OpB = Xp;          // 180 partials (Xp+Y contiguous)
  float* P0  = (float*)xn;  // xn+Qb contiguous = 16.78 MB fp32
  float* P1  = (float*)Ksw; // Ksw+Vsw contiguous

  const dim3 b256(256), b512(512);
  const dim3 convg(64, 4, 2);

  // ----- resnet 1 -----
  transpose_w<<<dim3(432, 16), b256, 0, stream>>>(r1_w1, wT, 13824, 512);
  norm_kernel<true, true><<<2890, b256, 0, stream>>>(x, r1_g1, Xp);
  conv_gemm_sp<<<convg, b256, 0, stream>>>(Xp, wT, P0, P1);
  transpose_w<<<dim3(432, 16), b256, 0, stream>>>(r1_w2, wT, 13824, 512);
  combine_norm<<<2890, b256, 0, stream>>>(P0, P1, r1_b1, r1_g2, Xp);
  conv_gemm_sp<<<convg, b256, 0, stream>>>(Xp, wT, P0, P1);
  conv_combine<true><<<4096, b256, 0, stream>>>(P0, P1, r1_b2, x, hA);

  // ----- attention -----
  norm_kernel<false, false><<<2048, b256, 0, stream>>>(hA, at_g, xn);
  transpose_w<<<dim3(16, 16), b256, 0, stream>>>(q_w, wqkvT, 512, 512);
  transpose_w<<<dim3(16, 16), b256, 0, stream>>>(k_w, wqkvT + 512 * 512, 512, 512);
  transpose_w<<<dim3(16, 16), b256, 0, stream>>>(v_w, wqkvT + 1024 * 512, 512, 512);
  transpose_w<<<dim3(16, 16), b256, 0, stream>>>(p_w, pwT, 512, 512);
  gemm_bt<0><<<dim3(64, 12), b256, 0, stream>>>(xn, wqkvT, 512, q_b, k_b, v_b,
                                                Qb, Ksw, Vsw, nullptr, nullptr);
  attn_partial<<<288, b512, 0, stream>>>(Qb, Ksw, Vsw, OpA, OpB, Lp);
  attn_combine<<<2048, b256, 0, stream>>>(OpA, OpB, Lp, xn);
  gemm_bt<1><<<dim3(64, 4), b256, 0, stream>>>(xn, pwT, 512, p_b, nullptr, nullptr,
                                               nullptr, nullptr, nullptr, hA, hA);

  // ----- resnet 2 -----
  transpose_w<<<dim3(432, 16), b256, 0, stream>>>(r2_w1, wT, 13824, 512);
  norm_kernel<true, true><<<2890, b256, 0, stream>>>(hA, r2_g1, Xp);
  conv_gemm_sp<<<convg, b256, 0, stream>>>(Xp, wT, P0, P1);
  transpose_w<<<dim3(432, 16), b256, 0, stream>>>(r2_w2, wT, 13824, 512);
  combine_norm<<<2890, b256, 0, stream>>>(P0, P1, r2_b1, r2_g2, Xp);
  conv_gemm_sp<<<convg, b256, 0, stream>>>(Xp, wT, P0, P1);
  conv_combine<true><<<4096, b256, 0, stream>>>(P0, P1, r2_b2, hA, out);
}

// Round 5
// 1068.421 us; speedup vs baseline: 2.2951x; 1.0542x over previous
//
#include <hip/hip_runtime.h>
#include <cstdint>
#include <cstddef>

// ---------------- types & helpers ----------------
typedef __attribute__((ext_vector_type(4))) float floatx4;
typedef __attribute__((ext_vector_type(8))) short short8;

__device__ __forceinline__ short f2bf(float x) {
  union { float f; unsigned u; } c; c.f = x;
  unsigned r = (c.u + 0x7FFFu + ((c.u >> 16) & 1u)) >> 16;  // RNE
  return (short)r;
}

__device__ __forceinline__ float bf2f(short x) {
  union { unsigned u; float f; } c; c.u = ((unsigned)(unsigned short)x) << 16;
  return c.f;
}

__device__ __forceinline__ floatx4 mfma16(short8 a, short8 b, floatx4 c) {
  return __builtin_amdgcn_mfma_f32_16x16x32_bf16(a, b, c, 0, 0, 0);
}

// async global->LDS, 16B per lane; LDS dest is wave-uniform base + lane*16
template <typename T>
__device__ __forceinline__ void gl_lds16(const T* g, T* l) {
  __builtin_amdgcn_global_load_lds(
      (__attribute__((address_space(1))) void*)g,
      (__attribute__((address_space(3))) void*)l, 16, 0, 0);
}

// ---------------- rmsnorm (+silu) with optional replicate-pad ----------------
template <bool PAD, bool SILU>
__global__ __launch_bounds__(256) void norm_kernel(const float* __restrict__ src,
                                                   const float* __restrict__ gamma,
                                                   short* __restrict__ dst) {
  const int tid = threadIdx.x;
  const int wv = tid >> 6, lane = tid & 63;
  const int id = blockIdx.x * 4 + wv;
  int srow;
  if (PAD) {
    int tp = id / 1156, rem = id - tp * 1156;
    int hp = rem / 34, wp = rem - hp * 34;
    int t = tp - 2; t = t < 0 ? 0 : t;
    int h = hp - 1; h = h < 0 ? 0 : (h > 31 ? 31 : h);
    int w = wp - 1; w = w < 0 ? 0 : (w > 31 ? 31 : w);
    srow = (t << 10) + (h << 5) + w;
  } else {
    srow = id;
  }
  const float* sp = src + (size_t)srow * 512 + lane * 8;
  float4 v0 = *(const float4*)sp;
  float4 v1 = *(const float4*)(sp + 4);
  float a[8] = {v0.x, v0.y, v0.z, v0.w, v1.x, v1.y, v1.z, v1.w};
  float ss = 0.f;
#pragma unroll
  for (int i = 0; i < 8; ++i) ss += a[i] * a[i];
#pragma unroll
  for (int off = 32; off > 0; off >>= 1) ss += __shfl_xor(ss, off);
  const float scale = 22.627416997969522f / (sqrtf(ss) + 1e-8f);  // sqrt(512)/(||x||+eps)
  const float* gp = gamma + lane * 8;
  float4 g0 = *(const float4*)gp;
  float4 g1 = *(const float4*)(gp + 4);
  float g[8] = {g0.x, g0.y, g0.z, g0.w, g1.x, g1.y, g1.z, g1.w};
  short8 ov;
#pragma unroll
  for (int i = 0; i < 8; ++i) {
    float y = a[i] * scale * g[i];
    if (SILU) y = y / (1.f + __expf(-y));
    ov[i] = f2bf(y);
  }
  *(short8*)(dst + (size_t)id * 512 + lane * 8) = ov;
}

// ---------------- fused split-K combine + rmsnorm + silu + replicate-pad ----------------
template <int NP>
__global__ __launch_bounds__(256) void combine_norm(const float* __restrict__ P0,
                                                    const float* __restrict__ P1,
                                                    const float* __restrict__ P2,
                                                    const float* __restrict__ bias,
                                                    const float* __restrict__ gamma,
                                                    short* __restrict__ dst) {
  const int tid = threadIdx.x;
  const int wv = tid >> 6, lane = tid & 63;
  const int id = blockIdx.x * 4 + wv;
  int tp = id / 1156, rem = id - tp * 1156;
  int hp = rem / 34, wp = rem - hp * 34;
  int t = tp - 2; t = t < 0 ? 0 : t;
  int h = hp - 1; h = h < 0 ? 0 : (h > 31 ? 31 : h);
  int w = wp - 1; w = w < 0 ? 0 : (w > 31 ? 31 : w);
  const size_t base = (size_t)((t << 10) + (h << 5) + w) * 512 + lane * 8;
  float a[8];
  {
    float4 a0 = *(const float4*)(P0 + base), a1 = *(const float4*)(P0 + base + 4);
    float4 b0 = *(const float4*)(P1 + base), b1 = *(const float4*)(P1 + base + 4);
    float4 z0 = *(const float4*)(bias + lane * 8), z1 = *(const float4*)(bias + lane * 8 + 4);
    a[0] = a0.x + b0.x + z0.x; a[1] = a0.y + b0.y + z0.y;
    a[2] = a0.z + b0.z + z0.z; a[3] = a0.w + b0.w + z0.w;
    a[4] = a1.x + b1.x + z1.x; a[5] = a1.y + b1.y + z1.y;
    a[6] = a1.z + b1.z + z1.z; a[7] = a1.w + b1.w + z1.w;
    if (NP == 3) {
      float4 c0 = *(const float4*)(P2 + base), c1 = *(const float4*)(P2 + base + 4);
      a[0] += c0.x; a[1] += c0.y; a[2] += c0.z; a[3] += c0.w;
      a[4] += c1.x; a[5] += c1.y; a[6] += c1.z; a[7] += c1.w;
    }
  }
  float ss = 0.f;
#pragma unroll
  for (int i = 0; i < 8; ++i) ss += a[i] * a[i];
#pragma unroll
  for (int off = 32; off > 0; off >>= 1) ss += __shfl_xor(ss, off);
  const float scale = 22.627416997969522f / (sqrtf(ss) + 1e-8f);
  float4 g0 = *(const float4*)(gamma + lane * 8), g1 = *(const float4*)(gamma + lane * 8 + 4);
  float g[8] = {g0.x, g0.y, g0.z, g0.w, g1.x, g1.y, g1.z, g1.w};
  short8 ov;
#pragma unroll
  for (int i = 0; i < 8; ++i) {
    float y = a[i] * scale * g[i];
    y = y / (1.f + __expf(-y));
    ov[i] = f2bf(y);
  }
  *(short8*)(dst + (size_t)id * 512 + lane * 8) = ov;
}

// ---------------- weight transpose fp32 [R][C] -> bf16 [C][R] ----------------
__global__ __launch_bounds__(256) void transpose_w(const float* __restrict__ src,
                                                   short* __restrict__ dst, int R, int C) {
  __shared__ float t[32][33];
  const int tx = threadIdx.x & 31, ty = threadIdx.x >> 5;
  const int r0 = (int)blockIdx.x << 5, c0 = (int)blockIdx.y << 5;
#pragma unroll
  for (int i = 0; i < 4; ++i)
    t[ty + i * 8][tx] = src[(size_t)(r0 + ty + i * 8) * C + c0 + tx];
  __syncthreads();
#pragma unroll
  for (int i = 0; i < 4; ++i)
    dst[(size_t)(c0 + ty + i * 8) * R + r0 + tx] = f2bf(t[tx][ty + i * 8]);
}

// ---------------- implicit-GEMM causal conv3d, split-K NP-way, dbuf prefetch ----------------
template <int NP>
__global__ __launch_bounds__(256) void conv_gemm_sp(const short* __restrict__ Xp,
                                                    const short* __restrict__ WT,
                                                    float* __restrict__ P0,
                                                    float* __restrict__ P1,
                                                    float* __restrict__ P2) {
  __shared__ __attribute__((aligned(16))) short Alds[2][4096];
  __shared__ __attribute__((aligned(16))) short Blds[2][4096];
  const int tid = threadIdx.x;
  const int wv = tid >> 6, lane = tid & 63;
  const int m0 = (int)blockIdx.x << 7, n0 = (int)blockIdx.y << 7;
  const int z = blockIdx.z;
  float* __restrict__ dst = (NP == 3) ? (z == 0 ? P0 : (z == 1 ? P1 : P2))
                                      : (z ? P1 : P0);

  int aoff[2], boff[2];
#pragma unroll
  for (int j = 0; j < 2; ++j) {
    const int chunk = wv * 2 + j;
    const int m = m0 + chunk * 16 + (lane >> 2);
    const int t = m >> 10, h = (m >> 5) & 31, w = m & 31;
    aoff[j] = (t * 1156 + h * 34 + w) * 512 + (lane & 3) * 8;
    const int n = n0 + chunk * 16 + (lane >> 2);
    boff[j] = n * 13824 + (lane & 3) * 8;
  }
  const int wm = (wv & 1) << 6, wn = (wv >> 1) << 6;
  floatx4 acc[4][4];
#pragma unroll
  for (int i = 0; i < 4; ++i)
#pragma unroll
    for (int j = 0; j < 4; ++j) acc[i][j] = 0.f;

  const int la = (lane & 15) * 32 + (lane >> 4) * 8;
  const int span = 432 / NP;
  const int k0 = z * span, k1 = k0 + span;

  auto stage = [&](int kk, int buf) {
    const int tap = kk >> 4;
    const int cin0 = (kk & 15) << 5;
    const int dt = tap / 9;
    const int r9 = tap - dt * 9;
    const int dh = r9 / 3;
    const int dw = r9 - dh * 3;
    const int tapoff = (dt * 1156 + dh * 34 + dw) * 512 + cin0;
#pragma unroll
    for (int j = 0; j < 2; ++j) {
      const int chunk = wv * 2 + j;
      gl_lds16(Xp + aoff[j] + tapoff, &Alds[buf][chunk * 512]);
      gl_lds16(WT + boff[j] + (kk << 5), &Blds[buf][chunk * 512]);
    }
  };

  stage(k0, 0);
  for (int kk = k0; kk < k1; ++kk) {
    const int cur = (kk - k0) & 1;
    __syncthreads();
    if (kk + 1 < k1) stage(kk + 1, cur ^ 1);
    short8 af[4], bf[4];
#pragma unroll
    for (int i = 0; i < 4; ++i) af[i] = *(const short8*)&Alds[cur][(wm + i * 16) * 32 + la];
#pragma unroll
    for (int j = 0; j < 4; ++j) bf[j] = *(const short8*)&Blds[cur][(wn + j * 16) * 32 + la];
#pragma unroll
    for (int i = 0; i < 4; ++i)
#pragma unroll
      for (int j = 0; j < 4; ++j) acc[i][j] = mfma16(af[i], bf[j], acc[i][j]);
  }

  const int rbase = m0 + wm + (lane >> 4) * 4;
#pragma unroll
  for (int i = 0; i < 4; ++i) {
    const int row = rbase + i * 16;
#pragma unroll
    for (int j = 0; j < 4; ++j) {
      const int col = n0 + wn + j * 16 + (lane & 15);
#pragma unroll
      for (int r = 0; r < 4; ++r)
        dst[(size_t)(row + r) * 512 + col] = acc[i][j][r];
    }
  }
}

template <int NP, bool HAS_RES>
__global__ __launch_bounds__(256) void conv_combine(const float* __restrict__ P0,
                                                    const float* __restrict__ P1,
                                                    const float* __restrict__ P2,
                                                    const float* __restrict__ bias,
                                                    const float* __restrict__ res,
                                                    float* __restrict__ out) {
  const size_t i = ((size_t)blockIdx.x * 256 + threadIdx.x) * 4;
  float4 a = *(const float4*)(P0 + i);
  float4 b = *(const float4*)(P1 + i);
  float4 bz = *(const float4*)(bias + (int)(i & 511));
  float4 r;
  r.x = a.x + b.x + bz.x;
  r.y = a.y + b.y + bz.y;
  r.z = a.z + b.z + bz.z;
  r.w = a.w + b.w + bz.w;
  if (NP == 3) {
    float4 c = *(const float4*)(P2 + i);
    r.x += c.x; r.y += c.y; r.z += c.z; r.w += c.w;
  }
  if (HAS_RES) {
    float4 rs = *(const float4*)(res + i);
    r.x += rs.x; r.y += rs.y; r.z += rs.z; r.w += rs.w;
  }
  *(float4*)(out + i) = r;
}

// ---------------- generic GEMM  C = A(MxK) * BT(NxK)^T, dbuf prefetch ----------------
// EPI=0: QKV — Q row-major bf16; K,V written pre-swizzled per 32-key tile:
//   K tile offset(key,c) = (c>>5)*1024 + ((c>>3)&3)*256 + key*8 + (c&7)
//   V tile offset(key,c) = ((key>>3)&3)*4096 + c*8 + (key&7)
// EPI=1: fp32 out = acc + bias + res (proj + identity; in-place-safe).
template <int EPI>
__global__ __launch_bounds__(256) void gemm_bt(const short* __restrict__ A,
                                               const short* __restrict__ BT, int kdim,
                                               const float* __restrict__ b0,
                                               const float* __restrict__ b1,
                                               const float* __restrict__ b2,
                                               short* __restrict__ o0,
                                               short* __restrict__ o1,
                                               short* __restrict__ o2,
                                               float* oF, const float* res) {
  __shared__ __attribute__((aligned(16))) short Alds[2][4096];
  __shared__ __attribute__((aligned(16))) short Blds[2][4096];
  const int tid = threadIdx.x;
  const int wv = tid >> 6, lane = tid & 63;
  const int m0 = (int)blockIdx.x << 7, n0 = (int)blockIdx.y << 7;
  int aoff[2], boff[2];
#pragma unroll
  for (int j = 0; j < 2; ++j) {
    const int chunk = wv * 2 + j;
    aoff[j] = (m0 + chunk * 16 + (lane >> 2)) * kdim + (lane & 3) * 8;
    boff[j] = (n0 + chunk * 16 + (lane >> 2)) * kdim + (lane & 3) * 8;
  }
  const int wm = (wv & 1) << 6, wn = (wv >> 1) << 6;
  floatx4 acc[4][4];
#pragma unroll
  for (int i = 0; i < 4; ++i)
#pragma unroll
    for (int j = 0; j < 4; ++j) acc[i][j] = 0.f;
  const int la = (lane & 15) * 32 + (lane >> 4) * 8;
  const int kiters = kdim >> 5;

  auto stage = [&](int kk, int buf) {
#pragma unroll
    for (int j = 0; j < 2; ++j) {
      const int chunk = wv * 2 + j;
      gl_lds16(A + aoff[j] + (kk << 5), &Alds[buf][chunk * 512]);
      gl_lds16(BT + boff[j] + (kk << 5), &Blds[buf][chunk * 512]);
    }
  };

  stage(0, 0);
  for (int kk = 0; kk < kiters; ++kk) {
    const int cur = kk & 1;
    __syncthreads();
    if (kk + 1 < kiters) stage(kk + 1, cur ^ 1);
    short8 af[4], bf[4];
#pragma unroll
    for (int i = 0; i < 4; ++i) af[i] = *(const short8*)&Alds[cur][(wm + i * 16) * 32 + la];
#pragma unroll
    for (int j = 0; j < 4; ++j) bf[j] = *(const short8*)&Blds[cur][(wn + j * 16) * 32 + la];
#pragma unroll
    for (int i = 0; i < 4; ++i)
#pragma unroll
      for (int j = 0; j < 4; ++j) acc[i][j] = mfma16(af[i], bf[j], acc[i][j]);
  }

  const int rbase = m0 + wm + (lane >> 4) * 4;
#pragma unroll
  for (int i = 0; i < 4; ++i) {
    const int row = rbase + i * 16;
#pragma unroll
    for (int j = 0; j < 4; ++j) {
      const int col = n0 + wn + j * 16 + (lane & 15);
      if (EPI == 0) {
        const int sel = col >> 9;
        const int c = col & 511;
        const float* bp = sel == 0 ? b0 : (sel == 1 ? b1 : b2);
        const float bz = bp[c];
#pragma unroll
        for (int r = 0; r < 4; ++r) {
          const int rr = row + r;
          const short v = f2bf(acc[i][j][r] + bz);
          if (sel == 0) {
            o0[(size_t)rr * 512 + c] = v;
          } else if (sel == 1) {
            o1[(size_t)(rr >> 5) * 16384 + ((c >> 5) << 10) + (((c >> 3) & 3) << 8) +
               ((rr & 31) << 3) + (c & 7)] = v;
          } else {
            o2[(size_t)(rr >> 5) * 16384 + (((rr >> 3) & 3) << 12) + (c << 3) + (rr & 7)] = v;
          }
        }
      } else {
        const float bz = b0[col];
#pragma unroll
        for (int r = 0; r < 4; ++r) {
          const size_t idx = (size_t)(row + r) * 512 + col;
          oF[idx] = acc[i][j][r] + bz + res[idx];
        }
      }
    }
  }
}

// ---------------- split-K flash attention partials ----------------
// block = 256 thr (4 waves) = 64 q x one 1024-key chunk; grid 576 @ 2 blocks/CU
// (no dispatch tail; cross-block overlap hides barrier drains). K+V staged in
// LDS (single buffer, 2 barriers/tile); fixed-max softmax (scores bounded ->
// m=0, no max shuffles, no rescale); l row-sum deferred to epilogue (linear).
__global__ __launch_bounds__(256, 2) void attn_partial(const short* __restrict__ Q,
                                                       const short* __restrict__ Ksw,
                                                       const short* __restrict__ Vsw,
                                                       short* __restrict__ OpA,
                                                       short* __restrict__ OpB,
                                                       float* __restrict__ Lp) {
  __shared__ __attribute__((aligned(16))) short Klds[16384];
  __shared__ __attribute__((aligned(16))) short Vlds[16384];
  __shared__ __attribute__((aligned(16))) short Plds[4][512];
  const int tid = threadIdx.x;
  const int wv = tid >> 6, lane = tid & 63;
  const int cl = lane & 15, quad = lane >> 4;
  // XCD-clustered mapping: xcd = bid & 7 (HW round-robin heuristic).
  const int bid = (int)blockIdx.x;
  const int x8 = bid & 7, jj = bid >> 3;
  int y, qb;
  if (jj < 64) {
    y = x8 + ((jj >> 4) << 3);
    qb = jj & 15;
  } else {
    const int L = x8 * 8 + (jj - 64);
    y = 32 + (L >> 4);
    qb = L & 15;
  }
  int f = 0;
  while ((f + 1) * (f + 2) / 2 <= y) ++f;
  const int chunk = y - f * (f + 1) / 2;
  const int pidx = y * 16 + qb;
  const int q0 = (f << 10) + (qb << 6);

  short8 qf[16];
  {
    const short* qp = Q + (size_t)(q0 + wv * 16 + cl) * 512 + quad * 8;
#pragma unroll
    for (int kc = 0; kc < 16; ++kc) qf[kc] = *(const short8*)(qp + kc * 32);
  }
  floatx4 o[32];
#pragma unroll
  for (int i = 0; i < 32; ++i) o[i] = 0.f;
  float lr[4] = {0.f, 0.f, 0.f, 0.f};
  const float c1 = 0.063758716f;  // log2(e)/sqrt(512)
  const short* klb = Klds + quad * 256 + cl * 8;
  const short* vlb = Vlds + quad * 4096 + cl * 8;
  const int swr = ((cl >> 1) & 3) << 3;

  for (int kt = 0; kt < 32; ++kt) {
    const size_t tb = (size_t)((chunk << 5) + kt) * 16384;
#pragma unroll
    for (int j = 0; j < 8; ++j) {
      const int row = (j * 4 + wv) << 9;
      gl_lds16(Ksw + tb + row + lane * 8, &Klds[row]);
      gl_lds16(Vsw + tb + row + lane * 8, &Vlds[row]);
    }
    __syncthreads();

    floatx4 s0 = 0.f, s1 = 0.f;
#pragma unroll
    for (int kc = 0; kc < 16; ++kc) {
      short8 k0 = *(const short8*)(klb + kc * 1024);
      short8 k1 = *(const short8*)(klb + kc * 1024 + 128);
      s0 = mfma16(qf[kc], k0, s0);
      s1 = mfma16(qf[kc], k1, s1);
    }

#pragma unroll
    for (int r = 0; r < 4; ++r) {
      const float p0 = exp2f(s0[r] * c1), p1 = exp2f(s1[r] * c1);
      lr[r] += p0 + p1;  // per-lane partial; row-sum deferred to epilogue
      const int qlr = quad * 4 + r;
      const int sw = ((qlr >> 1) & 3) << 3;
      const int oi = qlr * 32 + (cl ^ sw);
      Plds[wv][oi] = f2bf(p0);
      Plds[wv][oi ^ 16] = f2bf(p1);
    }
    const short8 pf = *(const short8*)&Plds[wv][cl * 32 + ((quad << 3) ^ swr)];
#pragma unroll
    for (int cn = 0; cn < 32; ++cn) {
      const short8 vf = *(const short8*)(vlb + cn * 128);
      o[cn] = mfma16(pf, vf, o[cn]);
    }
    __syncthreads();
  }

#pragma unroll
  for (int r = 0; r < 4; ++r) {
    float v = lr[r];
    v += __shfl_xor(v, 1);
    v += __shfl_xor(v, 2);
    v += __shfl_xor(v, 4);
    v += __shfl_xor(v, 8);
    lr[r] = v;
  }

  short* base = pidx < 216 ? OpA + (size_t)pidx * 32768 : OpB + (size_t)(pidx - 216) * 32768;
  const int lrow0 = wv * 16 + quad * 4;
#pragma unroll
  for (int cn = 0; cn < 32; ++cn) {
    const int col = cn * 16 + cl;
#pragma unroll
    for (int r = 0; r < 4; ++r)
      base[(size_t)(lrow0 + r) * 512 + col] = f2bf(o[cn][r]);
  }
  if (cl == 0) {
#pragma unroll
    for (int r = 0; r < 4; ++r) Lp[pidx * 64 + lrow0 + r] = lr[r];
  }
}

// ---------------- attention combine: merge up to 8 chunk partials ----------------
__global__ __launch_bounds__(256) void attn_combine(const short* __restrict__ OpA,
                                                    const short* __restrict__ OpB,
                                                    const float* __restrict__ Lp,
                                                    short* __restrict__ O) {
  const int tid = threadIdx.x;
  const int wv = tid >> 6, lane = tid & 63;
  const int row = (int)blockIdx.x * 4 + wv;
  const int f = row >> 10, n = f + 1;
  const int qb = (row >> 6) & 15, lrow = row & 63;
  const int tri = f * (f + 1) / 2;
  float den = 0.f, acc[8];
#pragma unroll
  for (int i = 0; i < 8; ++i) acc[i] = 0.f;
#pragma unroll
  for (int ch = 0; ch < 8; ++ch) {
    if (ch < n) {
      const int pidx = (tri + ch) * 16 + qb;
      den += Lp[pidx * 64 + lrow];
      const short* b = pidx < 216 ? OpA + (size_t)pidx * 32768 : OpB + (size_t)(pidx - 216) * 32768;
      const short8 v = *(const short8*)(b + (size_t)lrow * 512 + lane * 8);
#pragma unroll
      for (int i = 0; i < 8; ++i) acc[i] += bf2f(v[i]);
    }
  }
  const float inv = 1.f / den;
  short8 ov;
#pragma unroll
  for (int i = 0; i < 8; ++i) ov[i] = f2bf(acc[i] * inv);
  *(short8*)(O + (size_t)row * 512 + lane * 8) = ov;
}

// ---------------- host ----------------
extern "C" void kernel_launch(void* const* d_in, const int* in_sizes, int n_in,
                              void* d_out, int out_size, void* d_ws, size_t ws_size,
                              hipStream_t stream) {
  const float* x     = (const float*)d_in[0];
  const float* r1_g1 = (const float*)d_in[1];
  const float* r1_w1 = (const float*)d_in[2];
  const float* r1_b1 = (const float*)d_in[3];
  const float* r1_g2 = (const float*)d_in[4];
  const float* r1_w2 = (const float*)d_in[5];
  const float* r1_b2 = (const float*)d_in[6];
  const float* at_g  = (const float*)d_in[7];
  const float* q_w   = (const float*)d_in[8];
  const float* q_b   = (const float*)d_in[9];
  const float* k_w   = (const float*)d_in[10];
  const float* k_b   = (const float*)d_in[11];
  const float* v_w   = (const float*)d_in[12];
  const float* v_b   = (const float*)d_in[13];
  const float* p_w   = (const float*)d_in[14];
  const float* p_b   = (const float*)d_in[15];
  const float* r2_g1 = (const float*)d_in[16];
  const float* r2_w1 = (const float*)d_in[17];
  const float* r2_b1 = (const float*)d_in[18];
  const float* r2_g2 = (const float*)d_in[19];
  const float* r2_w2 = (const float*)d_in[20];
  const float* r2_b2 = (const float*)d_in[21];
  float* out = (float*)d_out;

  char* ws = (char*)d_ws;
  size_t off = 0;
  auto alloc = [&](size_t bytes) -> void* {
    void* p = ws + off;
    off = (off + bytes + 255) & ~(size_t)255;
    return p;
  };
  short* wT    = (short*)alloc(27ull * 512 * 512 * 2);      // 14.16 MB = 216 x 64KB attn partials
  short* wqkvT = (short*)alloc(1536ull * 512 * 2);
  short* pwT   = (short*)alloc(512ull * 512 * 2);
  short* Xp    = (short*)alloc(10ull * 34 * 34 * 512 * 2);  // padded act; Xp+Y = 360+ partials
  float* Y     = (float*)alloc(8192ull * 512 * 4);          // conv partial P2 (fp32)
  float* hA    = (float*)alloc(8192ull * 512 * 4);
  short* xn    = (short*)alloc(8192ull * 512 * 2);          // + Qb = conv partial P0 (fp32)
  short* Qb    = (short*)alloc(8192ull * 512 * 2);
  short* Ksw   = (short*)alloc(8192ull * 512 * 2);          // + Vsw = conv partial P1 (fp32)
  short* Vsw   = (short*)alloc(8192ull * 512 * 2);
  float* Lp    = (float*)alloc(576ull * 64 * 4);
  (void)ws_size; (void)in_sizes; (void)n_in; (void)out_size;

  short* OpA = wT;          // 216 partials of 64q x 512c bf16
  short* OpB = Xp;          // 360 partials (Xp+Y contiguous = 436 capacity)
  float* P0  = (float*)xn;  // xn+Qb contiguous = 16.78 MB fp32
  float* P1  = (float*)Ksw; // Ksw+Vsw contiguous
  float* P2  = Y;

  const dim3 b256(256);
  const dim3 convg3(64, 4, 3);  // split-K 3 (A/B test: resnet1)
  const dim3 convg2(64, 4, 2);  // split-K 2 (resnet2)

  // ----- resnet 1 (split-K 3) -----
  transpose_w<<<dim3(432, 16), b256, 0, stream>>>(r1_w1, wT, 13824, 512);
  norm_kernel<true, true><<<2890, b256, 0, stream>>>(x, r1_g1, Xp);
  conv_gemm_sp<3><<<convg3, b256, 0, stream>>>(Xp, wT, P0, P1, P2);
  transpose_w<<<dim3(432, 16), b256, 0, stream>>>(r1_w2, wT, 13824, 512);
  combine_norm<3><<<2890, b256, 0, stream>>>(P0, P1, P2, r1_b1, r1_g2, Xp);
  conv_gemm_sp<3><<<convg3, b256, 0, stream>>>(Xp, wT, P0, P1, P2);
  conv_combine<3, true><<<4096, b256, 0, stream>>>(P0, P1, P2, r1_b2, x, hA);

  // ----- attention -----
  norm_kernel<false, false><<<2048, b256, 0, stream>>>(hA, at_g, xn);
  transpose_w<<<dim3(16, 16), b256, 0, stream>>>(q_w, wqkvT, 512, 512);
  transpose_w<<<dim3(16, 16), b256, 0, stream>>>(k_w, wqkvT + 512 * 512, 512, 512);
  transpose_w<<<dim3(16, 16), b256, 0, stream>>>(v_w, wqkvT + 1024 * 512, 512, 512);
  transpose_w<<<dim3(16, 16), b256, 0, stream>>>(p_w, pwT, 512, 512);
  gemm_bt<0><<<dim3(64, 12), b256, 0, stream>>>(xn, wqkvT, 512, q_b, k_b, v_b,
                                                Qb, Ksw, Vsw, nullptr, nullptr);
  attn_partial<<<576, b256, 0, stream>>>(Qb, Ksw, Vsw, OpA, OpB, Lp);
  attn_combine<<<2048, b256, 0, stream>>>(OpA, OpB, Lp, xn);
  gemm_bt<1><<<dim3(64, 4), b256, 0, stream>>>(xn, pwT, 512, p_b, nullptr, nullptr,
                                               nullptr, nullptr, nullptr, hA, hA);

  // ----- resnet 2 (split-K 2) -----
  transpose_w<<<dim3(432, 16), b256, 0, stream>>>(r2_w1, wT, 13824, 512);
  norm_kernel<true, true><<<2890, b256, 0, stream>>>(hA, r2_g1, Xp);
  conv_gemm_sp<2><<<convg2, b256, 0, stream>>>(Xp, wT, P0, P1, P2);
  transpose_w<<<dim3(432, 16), b256, 0, stream>>>(r2_w2, wT, 13824, 512);
  combine_norm<2><<<2890, b256, 0, stream>>>(P0, P1, P2, r2_b1, r2_g2, Xp);
  conv_gemm_sp<2><<<convg2, b256, 0, stream>>>(Xp, wT, P0, P1, P2);
  conv_combine<2, true><<<4096, b256, 0, stream>>>(P0, P1, P2, r2_b2, hA, out);
}